// Round 1
// baseline (739.818 us; speedup 1.0000x reference)
//
#include <hip/hip_runtime.h>
#include <hip/hip_bf16.h>
#include <math.h>

#define B_ 8
#define T_ 2048
#define E_ 1024
#define H_ 128
#define M_ (B_*T_)   // 16384

// ---------------------------------------------------------------------------
// Kernel 1: QKV projection.  C[m,n] = sum_k x[m,k] * W[k,n]
// M=16384, K=1024, N=128.  Tile 128x128, KT=16, block 256 (16x16), micro 8x8.
// fp32 vector FMA (no fp32 MFMA on CDNA4).
// ---------------------------------------------------------------------------
__global__ __launch_bounds__(256) void qkv_proj(
    const float* __restrict__ x, const float* __restrict__ Wq,
    const float* __restrict__ Wk, const float* __restrict__ Wv,
    float* __restrict__ qo, float* __restrict__ ko, float* __restrict__ vo)
{
  const float* W; float* out;
  if (blockIdx.y == 0)      { W = Wq; out = qo; }
  else if (blockIdx.y == 1) { W = Wk; out = ko; }
  else                      { W = Wv; out = vo; }

  const int m0  = blockIdx.x * 128;
  const int tid = threadIdx.x;
  const int ty  = tid >> 4;     // 0..15, owns rows ty*8..ty*8+7
  const int tx  = tid & 15;     // 0..15, owns cols tx*8..tx*8+7

  // As[k][m] (transposed so compute reads are contiguous in m), pad 132
  __shared__ __align__(16) float As[16][132];
  __shared__ __align__(16) float Bs[16][132];

  float acc[8][8];
  #pragma unroll
  for (int i = 0; i < 8; ++i)
    #pragma unroll
    for (int j = 0; j < 8; ++j) acc[i][j] = 0.f;

  for (int k0 = 0; k0 < E_; k0 += 16) {
    // Load A tile: 128 rows x 16 k = 2048 floats = 512 float4, 2 per thread.
    #pragma unroll
    for (int u = 0; u < 2; ++u) {
      const int idx = u*256 + tid;
      const int row = idx >> 2;       // 0..127
      const int kq  = idx & 3;        // float4 index along k
      const float4 a = *(const float4*)(x + (size_t)(m0+row)*E_ + k0 + kq*4);
      As[kq*4+0][row] = a.x;
      As[kq*4+1][row] = a.y;
      As[kq*4+2][row] = a.z;
      As[kq*4+3][row] = a.w;
    }
    // Load B tile: 16 k x 128 n = 512 float4, 2 per thread (coalesced).
    #pragma unroll
    for (int u = 0; u < 2; ++u) {
      const int idx = u*256 + tid;
      const int kk = idx >> 5;        // 0..15
      const int c4 = idx & 31;        // 0..31
      *(float4*)&Bs[kk][c4*4] = *(const float4*)(W + (size_t)(k0+kk)*H_ + c4*4);
    }
    __syncthreads();

    #pragma unroll
    for (int kk = 0; kk < 16; ++kk) {
      const float4 a0 = *(const float4*)&As[kk][ty*8];
      const float4 a1 = *(const float4*)&As[kk][ty*8+4];
      const float4 b0 = *(const float4*)&Bs[kk][tx*8];
      const float4 b1 = *(const float4*)&Bs[kk][tx*8+4];
      const float a[8] = {a0.x,a0.y,a0.z,a0.w,a1.x,a1.y,a1.z,a1.w};
      const float b[8] = {b0.x,b0.y,b0.z,b0.w,b1.x,b1.y,b1.z,b1.w};
      #pragma unroll
      for (int i = 0; i < 8; ++i)
        #pragma unroll
        for (int j = 0; j < 8; ++j)
          acc[i][j] = fmaf(a[i], b[j], acc[i][j]);
    }
    __syncthreads();
  }

  #pragma unroll
  for (int i = 0; i < 8; ++i) {
    float* dst = out + (size_t)(m0 + ty*8 + i)*H_ + tx*8;
    *(float4*)dst     = make_float4(acc[i][0],acc[i][1],acc[i][2],acc[i][3]);
    *(float4*)(dst+4) = make_float4(acc[i][4],acc[i][5],acc[i][6],acc[i][7]);
  }
}

// ---------------------------------------------------------------------------
// Kernel 2: causal flash attention, fp32 online softmax.
// Q-tile 32, K-tile 64, block 256 (16x16).
// scores scaled by sqrt(T)=sqrt(2048) per the reference (very peaked softmax
// -> fp32 score precision is REQUIRED; see session notes).
// grid.x reversed so heavy (high-q) blocks launch first.
// LDS: Qt 18432 + KV(shared K/V buffer) 34816 + Pt 9216 = 62464 B < 64 KB.
// ---------------------------------------------------------------------------
__global__ __launch_bounds__(256) void flash_attn(
    const float* __restrict__ q, const float* __restrict__ k,
    const float* __restrict__ v, float* __restrict__ outp)
{
  const int b   = blockIdx.y;
  const int qt  = (T_/32 - 1) - (int)blockIdx.x;   // heavy first
  const int q0  = qt * 32;
  const int tid = threadIdx.x;
  const int ty  = tid >> 4;   // 0..15, owns rows ty*2, ty*2+1
  const int tx  = tid & 15;

  __shared__ __align__(16) float smQ[128*36];    // Qt[h][r], stride 36
  __shared__ __align__(16) float smKV[128*68];   // Kt[h][n] stride 68  OR  Vs[n][c] stride 132
  __shared__ __align__(16) float smP[64*36];     // Pt[j][r], stride 36

  // Load Q tile transposed: 32 rows x 128 h = 1024 float4, 4 per thread.
  #pragma unroll
  for (int u = 0; u < 4; ++u) {
    const int idx = u*256 + tid;
    const int r   = idx >> 5;        // 0..31
    const int h4  = idx & 31;
    const float4 a = *(const float4*)(q + (size_t)(b*T_ + q0 + r)*H_ + h4*4);
    smQ[(h4*4+0)*36 + r] = a.x;
    smQ[(h4*4+1)*36 + r] = a.y;
    smQ[(h4*4+2)*36 + r] = a.z;
    smQ[(h4*4+3)*36 + r] = a.w;
  }

  float m_st[2] = {-INFINITY, -INFINITY};
  float l_st[2] = {0.f, 0.f};
  float O[2][8];
  #pragma unroll
  for (int i = 0; i < 2; ++i)
    #pragma unroll
    for (int c = 0; c < 8; ++c) O[i][c] = 0.f;

  const int jt_max = (q0 + 31) >> 6;           // last k-tile (only one needing mask)
  const float SCALE = 45.25483399593904f;      // sqrt(2048)

  for (int jt = 0; jt <= jt_max; ++jt) {
    __syncthreads();  // prev-iter PV done with smKV (also fences Q load on iter 0)

    // Load K tile transposed: 64 rows x 128 h = 2048 float4, 8 per thread.
    #pragma unroll
    for (int u = 0; u < 8; ++u) {
      const int idx = u*256 + tid;
      const int n   = idx >> 5;      // 0..63
      const int h4  = idx & 31;
      const float4 a = *(const float4*)(k + (size_t)(b*T_ + jt*64 + n)*H_ + h4*4);
      smKV[(h4*4+0)*68 + n] = a.x;
      smKV[(h4*4+1)*68 + n] = a.y;
      smKV[(h4*4+2)*68 + n] = a.z;
      smKV[(h4*4+3)*68 + n] = a.w;
    }
    __syncthreads();

    // S = Q K^T : rows ty*2+i, cols tx*4+j, reduce over h=128.
    float s[2][4] = {{0,0,0,0},{0,0,0,0}};
    #pragma unroll 8
    for (int h = 0; h < 128; ++h) {
      const float2 a  = *(const float2*)&smQ[h*36 + ty*2];
      const float4 bb = *(const float4*)&smKV[h*68 + tx*4];
      s[0][0] = fmaf(a.x, bb.x, s[0][0]);
      s[0][1] = fmaf(a.x, bb.y, s[0][1]);
      s[0][2] = fmaf(a.x, bb.z, s[0][2]);
      s[0][3] = fmaf(a.x, bb.w, s[0][3]);
      s[1][0] = fmaf(a.y, bb.x, s[1][0]);
      s[1][1] = fmaf(a.y, bb.y, s[1][1]);
      s[1][2] = fmaf(a.y, bb.z, s[1][2]);
      s[1][3] = fmaf(a.y, bb.w, s[1][3]);
    }

    #pragma unroll
    for (int i = 0; i < 2; ++i)
      #pragma unroll
      for (int j = 0; j < 4; ++j) s[i][j] *= SCALE;

    if (jt == jt_max) {   // only the last tile can contain masked keys
      #pragma unroll
      for (int i = 0; i < 2; ++i)
        #pragma unroll
        for (int j = 0; j < 4; ++j)
          if (jt*64 + tx*4 + j > q0 + ty*2 + i) s[i][j] = -INFINITY;
    }

    // Online softmax (per-row state replicated across the 16 tx lanes;
    // xor-shuffle reductions stay within the 16 consecutive lanes of a ty group).
    #pragma unroll
    for (int i = 0; i < 2; ++i) {
      float rm = fmaxf(fmaxf(s[i][0], s[i][1]), fmaxf(s[i][2], s[i][3]));
      rm = fmaxf(rm, __shfl_xor(rm, 1));
      rm = fmaxf(rm, __shfl_xor(rm, 2));
      rm = fmaxf(rm, __shfl_xor(rm, 4));
      rm = fmaxf(rm, __shfl_xor(rm, 8));
      const float mnew  = fmaxf(m_st[i], rm);
      const float alpha = __expf(m_st[i] - mnew);   // exp(-inf)=0 on first iter
      float p0 = __expf(s[i][0] - mnew);
      float p1 = __expf(s[i][1] - mnew);
      float p2 = __expf(s[i][2] - mnew);
      float p3 = __expf(s[i][3] - mnew);
      smP[(tx*4+0)*36 + ty*2 + i] = p0;
      smP[(tx*4+1)*36 + ty*2 + i] = p1;
      smP[(tx*4+2)*36 + ty*2 + i] = p2;
      smP[(tx*4+3)*36 + ty*2 + i] = p3;
      float sum = (p0 + p1) + (p2 + p3);
      sum += __shfl_xor(sum, 1);
      sum += __shfl_xor(sum, 2);
      sum += __shfl_xor(sum, 4);
      sum += __shfl_xor(sum, 8);
      l_st[i] = l_st[i]*alpha + sum;
      m_st[i] = mnew;
      #pragma unroll
      for (int c = 0; c < 8; ++c) O[i][c] *= alpha;
    }
    __syncthreads();   // everyone done reading Kt and writing Pt

    // Load V tile into the same buffer: Vs[n][c], stride 132.
    #pragma unroll
    for (int u = 0; u < 8; ++u) {
      const int idx = u*256 + tid;
      const int n   = idx >> 5;      // 0..63
      const int c4  = idx & 31;
      *(float4*)&smKV[n*132 + c4*4] =
          *(const float4*)(v + (size_t)(b*T_ + jt*64 + n)*H_ + c4*4);
    }
    __syncthreads();

    // O[r][c] += P[j][r] * V[j][c]
    #pragma unroll 4
    for (int j = 0; j < 64; ++j) {
      const float2 pp = *(const float2*)&smP[j*36 + ty*2];
      const float4 v0 = *(const float4*)&smKV[j*132 + tx*8];
      const float4 v1 = *(const float4*)&smKV[j*132 + tx*8 + 4];
      O[0][0] = fmaf(pp.x, v0.x, O[0][0]);
      O[0][1] = fmaf(pp.x, v0.y, O[0][1]);
      O[0][2] = fmaf(pp.x, v0.z, O[0][2]);
      O[0][3] = fmaf(pp.x, v0.w, O[0][3]);
      O[0][4] = fmaf(pp.x, v1.x, O[0][4]);
      O[0][5] = fmaf(pp.x, v1.y, O[0][5]);
      O[0][6] = fmaf(pp.x, v1.z, O[0][6]);
      O[0][7] = fmaf(pp.x, v1.w, O[0][7]);
      O[1][0] = fmaf(pp.y, v0.x, O[1][0]);
      O[1][1] = fmaf(pp.y, v0.y, O[1][1]);
      O[1][2] = fmaf(pp.y, v0.z, O[1][2]);
      O[1][3] = fmaf(pp.y, v0.w, O[1][3]);
      O[1][4] = fmaf(pp.y, v1.x, O[1][4]);
      O[1][5] = fmaf(pp.y, v1.y, O[1][5]);
      O[1][6] = fmaf(pp.y, v1.z, O[1][6]);
      O[1][7] = fmaf(pp.y, v1.w, O[1][7]);
    }
  }

  #pragma unroll
  for (int i = 0; i < 2; ++i) {
    const float inv = 1.0f / l_st[i];    // l>0 always (diagonal key is unmasked)
    const int row = q0 + ty*2 + i;
    float* dst = outp + (size_t)(b*T_ + row)*H_ + tx*8;
    *(float4*)dst     = make_float4(O[i][0]*inv, O[i][1]*inv, O[i][2]*inv, O[i][3]*inv);
    *(float4*)(dst+4) = make_float4(O[i][4]*inv, O[i][5]*inv, O[i][6]*inv, O[i][7]*inv);
  }
}

// ---------------------------------------------------------------------------
extern "C" void kernel_launch(void* const* d_in, const int* in_sizes, int n_in,
                              void* d_out, int out_size, void* d_ws, size_t ws_size,
                              hipStream_t stream) {
  (void)in_sizes; (void)n_in; (void)out_size; (void)ws_size;
  const float* x  = (const float*)d_in[0];
  const float* Wq = (const float*)d_in[1];
  const float* Wk = (const float*)d_in[2];
  const float* Wv = (const float*)d_in[3];
  float* out = (float*)d_out;

  // workspace: q | k | v, each M_*H_ fp32  (24 MB total)
  float* qb = (float*)d_ws;
  float* kb = qb + (size_t)M_*H_;
  float* vb = kb + (size_t)M_*H_;

  qkv_proj<<<dim3(M_/128, 3), 256, 0, stream>>>(x, Wq, Wk, Wv, qb, kb, vb);
  flash_attn<<<dim3(T_/32, B_), 256, 0, stream>>>(qb, kb, vb, out);
}

// Round 3
// 285.295 us; speedup vs baseline: 2.5932x; 2.5932x over previous
//
#include <hip/hip_runtime.h>
#include <hip/hip_bf16.h>
#include <math.h>

#define B_ 8
#define T_ 2048
#define E_ 1024
#define H_ 128
#define M_ (B_*T_)              // 16384
#define SCALE_ 45.25483399593904f   // sqrt(2048) per reference

typedef __attribute__((ext_vector_type(8))) short bf16x8;
typedef __attribute__((ext_vector_type(4))) float f32x4;

__device__ __forceinline__ ushort bf16_rne(float f) {
  unsigned u = __float_as_uint(f);
  u += 0x7fffu + ((u >> 16) & 1u);
  return (ushort)(u >> 16);
}
__device__ __forceinline__ float bf16_tof(ushort h) {
  return __uint_as_float(((unsigned)h) << 16);
}

// ---------------------------------------------------------------------------
// Kernel 0: split W (fp32 [k][n] per matrix) -> whT/wlT bf16 [mat][n][k].
// Transposed so GEMM B-fragments are 16B-contiguous in k.
// ---------------------------------------------------------------------------
__global__ __launch_bounds__(256) void wsplit(
    const float* __restrict__ Wq, const float* __restrict__ Wk,
    const float* __restrict__ Wv,
    ushort* __restrict__ whT, ushort* __restrict__ wlT)
{
  const int idx = blockIdx.x * 256 + threadIdx.x;   // 0 .. 49151
  const int mat = idx / 16384;                      // 128 n * 128 k-chunks
  const int rem = idx % 16384;
  const int n   = rem >> 7;
  const int k0  = (rem & 127) * 8;
  const float* W = (mat == 0) ? Wq : (mat == 1) ? Wk : Wv;
  bf16x8 hv, lv;
  #pragma unroll
  for (int j = 0; j < 8; ++j) {
    const float f = W[(size_t)(k0 + j) * H_ + n];
    const ushort h = bf16_rne(f);
    hv[j] = (short)h;
    lv[j] = (short)bf16_rne(f - bf16_tof(h));
  }
  const size_t off = ((size_t)mat * H_ + n) * E_ + k0;
  *(bf16x8*)(whT + off) = hv;
  *(bf16x8*)(wlT + off) = lv;
}

// ---------------------------------------------------------------------------
// Kernel 1: QKV projection via split-bf16 MFMA (3-term: hh + hl + lh).
// Tile 64m x 128n, BK=32, block 256 (4 waves, wave w owns rows w*16..+15).
// x is split to hi/lo bf16 on the fly during LDS staging.
// Epilogue: mat 0/1 -> split bf16 q/k in [t][h]; mat 2 -> bf16 v transposed
// to [b][h][t] (via LDS) so attention V-fragments are contiguous.
// ---------------------------------------------------------------------------
__global__ __launch_bounds__(256) void proj_mfma(
    const float* __restrict__ x,
    const ushort* __restrict__ whT, const ushort* __restrict__ wlT,
    ushort* __restrict__ qh, ushort* __restrict__ ql,
    ushort* __restrict__ kh, ushort* __restrict__ kl,
    ushort* __restrict__ vT)
{
  const int mat = blockIdx.y;
  const int m0  = blockIdx.x * 64;
  const int tid = threadIdx.x;
  const int wave = tid >> 6, lane = tid & 63;
  const int quad = lane >> 4, l15 = lane & 15;

  __shared__ __align__(16) ushort sm[12288];   // 24 KB
  ushort* Ah = sm;            // [64][32]
  ushort* Al = sm + 2048;     // [64][32]
  ushort* Bh = sm + 4096;     // [128][32]  (W^T tile: [n][k])
  ushort* Bl = sm + 8192;     // [128][32]

  const ushort* bhp = whT + (size_t)mat * H_ * E_;
  const ushort* blp = wlT + (size_t)mat * H_ * E_;

  f32x4 acc[8];
  #pragma unroll
  for (int i = 0; i < 8; ++i) acc[i] = (f32x4){0.f, 0.f, 0.f, 0.f};

  const int arow  = tid >> 2;          // 0..63
  const int akoff = (tid & 3) * 8;     // 0,8,16,24

  for (int k0 = 0; k0 < E_; k0 += 32) {
    // stage A (x fp32 -> split bf16), 64x32
    {
      const float* src = x + (size_t)(m0 + arow) * E_ + k0 + akoff;
      const float4 f0 = *(const float4*)src;
      const float4 f1 = *(const float4*)(src + 4);
      const float f[8] = {f0.x, f0.y, f0.z, f0.w, f1.x, f1.y, f1.z, f1.w};
      bf16x8 hv, lv;
      #pragma unroll
      for (int j = 0; j < 8; ++j) {
        const ushort h = bf16_rne(f[j]);
        hv[j] = (short)h;
        lv[j] = (short)bf16_rne(f[j] - bf16_tof(h));
      }
      *(bf16x8*)&Ah[arow * 32 + akoff] = hv;
      *(bf16x8*)&Al[arow * 32 + akoff] = lv;
    }
    // stage B (pre-split W^T), 128x32 x2
    #pragma unroll
    for (int u = 0; u < 2; ++u) {
      const int i2  = u * 256 + tid;
      const int nr  = i2 >> 2;
      const int bk  = (i2 & 3) * 8;
      *(bf16x8*)&Bh[nr * 32 + bk] = *(const bf16x8*)(bhp + (size_t)nr * E_ + k0 + bk);
      *(bf16x8*)&Bl[nr * 32 + bk] = *(const bf16x8*)(blp + (size_t)nr * E_ + k0 + bk);
    }
    __syncthreads();

    const bf16x8 a_h = *(const bf16x8*)&Ah[(wave * 16 + l15) * 32 + quad * 8];
    const bf16x8 a_l = *(const bf16x8*)&Al[(wave * 16 + l15) * 32 + quad * 8];
    #pragma unroll
    for (int nt = 0; nt < 8; ++nt) {
      const bf16x8 b_h = *(const bf16x8*)&Bh[(nt * 16 + l15) * 32 + quad * 8];
      const bf16x8 b_l = *(const bf16x8*)&Bl[(nt * 16 + l15) * 32 + quad * 8];
      acc[nt] = __builtin_amdgcn_mfma_f32_16x16x32_bf16(a_h, b_h, acc[nt], 0, 0, 0);
      acc[nt] = __builtin_amdgcn_mfma_f32_16x16x32_bf16(a_h, b_l, acc[nt], 0, 0, 0);
      acc[nt] = __builtin_amdgcn_mfma_f32_16x16x32_bf16(a_l, b_h, acc[nt], 0, 0, 0);
    }
    __syncthreads();
  }

  // Epilogue. C/D: row = quad*4+reg (m within 16-tile), col = l15 (n within 16-tile).
  const int mrow = wave * 16 + quad * 4;
  if (mat < 2) {
    ushort* oh = (mat == 0) ? qh : kh;
    ushort* ol = (mat == 0) ? ql : kl;
    #pragma unroll
    for (int nt = 0; nt < 8; ++nt)
      #pragma unroll
      for (int r = 0; r < 4; ++r) {
        const float a = acc[nt][r];
        const ushort h = bf16_rne(a);
        const size_t off = (size_t)(m0 + mrow + r) * H_ + nt * 16 + l15;
        oh[off] = h;
        ol[off] = bf16_rne(a - bf16_tof(h));
      }
  } else {
    // v: transpose 64t x 128h tile through LDS, write vT[b][h][t] coalesced.
    __syncthreads();
    ushort* smT = sm;                       // [128][64]
    #pragma unroll
    for (int nt = 0; nt < 8; ++nt)
      #pragma unroll
      for (int r = 0; r < 4; ++r)
        smT[(nt * 16 + l15) * 64 + mrow + r] = bf16_rne(acc[nt][r]);
    __syncthreads();
    const int b  = m0 >> 11;
    const int t0 = m0 & 2047;
    // 8192 elements = 1024 chunks of 8 ushorts (bf16x8 = 8 elements = 16 B).
    // (round-2 bug: used 16-element chunk offsets with 8-element copies ->
    //  half of vT left 0xAA-poisoned -> absmax ~= ref absmax)
    #pragma unroll
    for (int u = 0; u < 4; ++u) {
      const int c    = u * 256 + tid;       // 0..1023
      const int n    = c >> 3;              // h index 0..127
      const int toff = (c & 7) * 8;         // 0..56 step 8
      *(bf16x8*)(vT + ((size_t)b * H_ + n) * T_ + t0 + toff) =
          *(const bf16x8*)&smT[n * 64 + toff];
    }
  }
}

// ---------------------------------------------------------------------------
// Kernel 2: causal flash attention, bf16-split MFMA, fp32 online softmax.
// One wave per 16 query rows. grid (8=batch, 128=qtile) -> linear%8 = batch
// pins each batch to one XCD (its 1.5MB K/V set fits the 4MB XCD L2).
// All Q/K/V fragments load straight from global in MFMA layout (16B/lane);
// only P round-trips through a per-wave 16x40 LDS tile (m120 pattern).
// MFMA layouts (verified, guide §3): A[m=lane&15][k=quad*8+j],
// B[k=quad*8+j][n=lane&15], C/D row=quad*4+reg, col=lane&15.
// ---------------------------------------------------------------------------
__global__ __launch_bounds__(64) void attn_mfma(
    const ushort* __restrict__ qh, const ushort* __restrict__ ql,
    const ushort* __restrict__ kh, const ushort* __restrict__ kl,
    const ushort* __restrict__ vT, float* __restrict__ out)
{
  const int b    = blockIdx.x;
  const int qt   = (int)gridDim.y - 1 - (int)blockIdx.y;   // heavy first
  const int q0   = qt * 16;
  const int lane = threadIdx.x;
  const int quad = lane >> 4, l15 = lane & 15;

  __shared__ __align__(16) ushort smP[16][40];   // [q][key], stride 40 (80B, 16B-aligned rows)

  const size_t base = (size_t)b * T_ * H_;

  // Q fragments (persistent): rows q0+l15, h-chunks of 32.
  const ushort* qhp = qh + base + (size_t)(q0 + l15) * H_ + quad * 8;
  const ushort* qlp = ql + base + (size_t)(q0 + l15) * H_ + quad * 8;
  bf16x8 Qh[4], Ql[4];
  #pragma unroll
  for (int c = 0; c < 4; ++c) {
    Qh[c] = *(const bf16x8*)(qhp + c * 32);
    Ql[c] = *(const bf16x8*)(qlp + c * 32);
  }

  f32x4 O[8];
  #pragma unroll
  for (int i = 0; i < 8; ++i) O[i] = (f32x4){0.f, 0.f, 0.f, 0.f};
  float mstate[4] = {-1e30f, -1e30f, -1e30f, -1e30f};
  float lstate[4] = {0.f, 0.f, 0.f, 0.f};

  const int ntiles = (q0 >> 5) + 1;   // 32-key tiles covering keys 0..q0+15

  for (int jt = 0; jt < ntiles; ++jt) {
    const int k0 = jt * 32;
    const ushort* khp = kh + base + (size_t)k0 * H_ + quad * 8;
    const ushort* klp = kl + base + (size_t)k0 * H_ + quad * 8;

    bf16x8 Kh0[4], Kh1[4], Kl0[4], Kl1[4];
    #pragma unroll
    for (int c = 0; c < 4; ++c) {
      Kh0[c] = *(const bf16x8*)(khp + (size_t)l15 * H_ + c * 32);
      Kh1[c] = *(const bf16x8*)(khp + (size_t)(16 + l15) * H_ + c * 32);
      Kl0[c] = *(const bf16x8*)(klp + (size_t)l15 * H_ + c * 32);
      Kl1[c] = *(const bf16x8*)(klp + (size_t)(16 + l15) * H_ + c * 32);
    }
    bf16x8 Vf[8];
    #pragma unroll
    for (int ct = 0; ct < 8; ++ct)
      Vf[ct] = *(const bf16x8*)(vT + base + (size_t)(ct * 16 + l15) * T_ + k0 + quad * 8);

    // S = Q K^T, split into hh-chain (len 4) and cross-chain (len 8) per subtile.
    f32x4 shh0 = (f32x4){0,0,0,0}, shh1 = (f32x4){0,0,0,0};
    f32x4 sx0  = (f32x4){0,0,0,0}, sx1  = (f32x4){0,0,0,0};
    #pragma unroll
    for (int c = 0; c < 4; ++c) {
      shh0 = __builtin_amdgcn_mfma_f32_16x16x32_bf16(Qh[c], Kh0[c], shh0, 0, 0, 0);
      shh1 = __builtin_amdgcn_mfma_f32_16x16x32_bf16(Qh[c], Kh1[c], shh1, 0, 0, 0);
      sx0  = __builtin_amdgcn_mfma_f32_16x16x32_bf16(Qh[c], Kl0[c], sx0, 0, 0, 0);
      sx1  = __builtin_amdgcn_mfma_f32_16x16x32_bf16(Qh[c], Kl1[c], sx1, 0, 0, 0);
      sx0  = __builtin_amdgcn_mfma_f32_16x16x32_bf16(Ql[c], Kh0[c], sx0, 0, 0, 0);
      sx1  = __builtin_amdgcn_mfma_f32_16x16x32_bf16(Ql[c], Kh1[c], sx1, 0, 0, 0);
    }

    float s0[4], s1[4];
    #pragma unroll
    for (int r = 0; r < 4; ++r) {
      s0[r] = (shh0[r] + sx0[r]) * SCALE_;
      s1[r] = (shh1[r] + sx1[r]) * SCALE_;
    }
    if (jt == ntiles - 1) {           // only the last tile can contain masked keys
      const int krel0 = k0 + l15      - q0 - quad * 4;
      const int krel1 = k0 + 16 + l15 - q0 - quad * 4;
      #pragma unroll
      for (int r = 0; r < 4; ++r) {
        if (krel0 > r) s0[r] = -1e30f;
        if (krel1 > r) s1[r] = -1e30f;
      }
    }

    float alpha[4], p0[4], p1[4], psum[4];
    #pragma unroll
    for (int r = 0; r < 4; ++r) {
      float rm = fmaxf(s0[r], s1[r]);
      rm = fmaxf(rm, __shfl_xor(rm, 1));
      rm = fmaxf(rm, __shfl_xor(rm, 2));
      rm = fmaxf(rm, __shfl_xor(rm, 4));
      rm = fmaxf(rm, __shfl_xor(rm, 8));
      const float mnew = fmaxf(mstate[r], rm);
      alpha[r] = __expf(mstate[r] - mnew);
      mstate[r] = mnew;
      p0[r] = __expf(s0[r] - mnew);
      p1[r] = __expf(s1[r] - mnew);
      float su = p0[r] + p1[r];
      su += __shfl_xor(su, 1);
      su += __shfl_xor(su, 2);
      su += __shfl_xor(su, 4);
      su += __shfl_xor(su, 8);
      psum[r] = su;
    }
    #pragma unroll
    for (int r = 0; r < 4; ++r) {
      lstate[r] = lstate[r] * alpha[r] + psum[r];
      smP[quad * 4 + r][l15]      = bf16_rne(p0[r]);
      smP[quad * 4 + r][16 + l15] = bf16_rne(p1[r]);
    }
    #pragma unroll
    for (int ct = 0; ct < 8; ++ct) {
      O[ct][0] *= alpha[0]; O[ct][1] *= alpha[1];
      O[ct][2] *= alpha[2]; O[ct][3] *= alpha[3];
    }
    // P back out in A-layout (wave-synchronous LDS round-trip, no barrier needed)
    const bf16x8 pA = *(const bf16x8*)&smP[l15][quad * 8];
    #pragma unroll
    for (int ct = 0; ct < 8; ++ct)
      O[ct] = __builtin_amdgcn_mfma_f32_16x16x32_bf16(pA, Vf[ct], O[ct], 0, 0, 0);
  }

  #pragma unroll
  for (int r = 0; r < 4; ++r) {
    const float inv = 1.0f / lstate[r];
    #pragma unroll
    for (int ct = 0; ct < 8; ++ct)
      out[base + (size_t)(q0 + quad * 4 + r) * H_ + ct * 16 + l15] = O[ct][r] * inv;
  }
}

// ---------------------------------------------------------------------------
extern "C" void kernel_launch(void* const* d_in, const int* in_sizes, int n_in,
                              void* d_out, int out_size, void* d_ws, size_t ws_size,
                              hipStream_t stream) {
  (void)in_sizes; (void)n_in; (void)out_size; (void)ws_size;
  const float* x  = (const float*)d_in[0];
  const float* Wq = (const float*)d_in[1];
  const float* Wk = (const float*)d_in[2];
  const float* Wv = (const float*)d_in[3];
  float* out = (float*)d_out;

  // workspace layout (bf16/ushort elements):
  //   qh, ql, kh, kl : M_*H_ each (4 MB each)
  //   vT             : M_*H_     (4 MB, [b][h][t])
  //   whT, wlT       : 3*H_*E_   (0.75 MB each)
  // total ~21.5 MB
  ushort* qhb = (ushort*)d_ws;
  ushort* qlb = qhb + (size_t)M_ * H_;
  ushort* khb = qlb + (size_t)M_ * H_;
  ushort* klb = khb + (size_t)M_ * H_;
  ushort* vTb = klb + (size_t)M_ * H_;
  ushort* whT = vTb + (size_t)M_ * H_;
  ushort* wlT = whT + (size_t)3 * H_ * E_;

  wsplit<<<dim3(192), 256, 0, stream>>>(Wq, Wk, Wv, whT, wlT);
  proj_mfma<<<dim3(M_/64, 3), 256, 0, stream>>>(x, whT, wlT,
                                                qhb, qlb, khb, klb, vTb);
  attn_mfma<<<dim3(B_, T_/16), 64, 0, stream>>>(qhb, qlb, khb, klb, vTb, out);
}

// Round 5
// 271.610 us; speedup vs baseline: 2.7238x; 1.0504x over previous
//
#include <hip/hip_runtime.h>
#include <hip/hip_bf16.h>
#include <math.h>

#define B_ 8
#define T_ 2048
#define E_ 1024
#define H_ 128
#define M_ (B_*T_)              // 16384
#define SCALE_ 45.25483399593904f   // sqrt(2048) per reference

typedef __attribute__((ext_vector_type(8))) short bf16x8;
typedef __attribute__((ext_vector_type(4))) float f32x4;

#define mfma16(A, Bv, C) __builtin_amdgcn_mfma_f32_16x16x32_bf16((A), (Bv), (C), 0, 0, 0)

__device__ __forceinline__ ushort bf16_rne(float f) {
  unsigned u = __float_as_uint(f);
  u += 0x7fffu + ((u >> 16) & 1u);
  return (ushort)(u >> 16);
}
__device__ __forceinline__ float bf16_tof(ushort h) {
  return __uint_as_float(((unsigned)h) << 16);
}

// DPP row_ror:N within 16-lane rows (VALU-latency cross-lane; replaces
// ds_swizzle-based __shfl_xor at ~120cyc with ~8cyc ops).
template <int N>
__device__ __forceinline__ float ror16(float x) {
  return __uint_as_float((unsigned)__builtin_amdgcn_update_dpp(
      0, (int)__float_as_uint(x), 0x120 + N, 0xF, 0xF, true));
}
__device__ __forceinline__ float rowmax16(float x) {
  x = fmaxf(x, ror16<8>(x));
  x = fmaxf(x, ror16<4>(x));
  x = fmaxf(x, ror16<2>(x));
  x = fmaxf(x, ror16<1>(x));
  return x;
}
__device__ __forceinline__ float rowsum16(float x) {
  x += ror16<8>(x);
  x += ror16<4>(x);
  x += ror16<2>(x);
  x += ror16<1>(x);
  return x;
}

// ---------------------------------------------------------------------------
// Kernel 0: split W (fp32 [k][n] per matrix) -> whT/wlT bf16 [mat][n][k].
// ---------------------------------------------------------------------------
__global__ __launch_bounds__(256) void wsplit(
    const float* __restrict__ Wq, const float* __restrict__ Wk,
    const float* __restrict__ Wv,
    ushort* __restrict__ whT, ushort* __restrict__ wlT)
{
  const int idx = blockIdx.x * 256 + threadIdx.x;   // 0 .. 49151
  const int mat = idx / 16384;
  const int rem = idx % 16384;
  const int n   = rem >> 7;
  const int k0  = (rem & 127) * 8;
  const float* W = (mat == 0) ? Wq : (mat == 1) ? Wk : Wv;
  bf16x8 hv, lv;
  #pragma unroll
  for (int j = 0; j < 8; ++j) {
    const float f = W[(size_t)(k0 + j) * H_ + n];
    const ushort h = bf16_rne(f);
    hv[j] = (short)h;
    lv[j] = (short)bf16_rne(f - bf16_tof(h));
  }
  const size_t off = ((size_t)mat * H_ + n) * E_ + k0;
  *(bf16x8*)(whT + off) = hv;
  *(bf16x8*)(wlT + off) = lv;
}

// ---------------------------------------------------------------------------
// Kernel 1: FUSED QKV projection. One block computes 64 m-rows x all 384
// output cols (q|k|v). A (x) staged/split ONCE per tile. q,k use 3-term
// split MFMA; v uses 1-term. Wave w owns ntiles {w, w+4, ..., w+20}.
// LDS rows padded to 40 elems (80B).
// ROUND-5 FIX: B staging chunk counts were half the tile (u<3 / u<2 ->
// rows 192..383 of Bh and 128..255 of Bl left UNINITIALIZED -> garbage k,v,
// absmax 11). Correct counts: Bh 384rows*4chunks=1536 (u<6), Bl 1024 (u<4).
// Same bug class as round 2: staging-loop chunk arithmetic — now triple-
// checked: elements = rows*32; chunks = elements/8; iterations = chunks/256.
// ---------------------------------------------------------------------------
__global__ __launch_bounds__(256) void proj_fused(
    const float* __restrict__ x,
    const ushort* __restrict__ whT, const ushort* __restrict__ wlT,
    ushort* __restrict__ qh, ushort* __restrict__ ql,
    ushort* __restrict__ kh, ushort* __restrict__ kl,
    ushort* __restrict__ vT)
{
  const int m0  = blockIdx.x * 64;
  const int tid = threadIdx.x;
  const int wave = tid >> 6, lane = tid & 63;
  const int quad = lane >> 4, l15 = lane & 15;

  __shared__ __align__(16) ushort AhS[64 * 40];    //  5.0 KB
  __shared__ __align__(16) ushort AlS[64 * 40];    //  5.0 KB
  __shared__ __align__(16) ushort BhS[384 * 40];   // 30.0 KB
  __shared__ __align__(16) ushort BlS[256 * 40];   // 20.0 KB  (q,k rows only)

  f32x4 acc[6][4];
  #pragma unroll
  for (int j = 0; j < 6; ++j)
    #pragma unroll
    for (int mt = 0; mt < 4; ++mt) acc[j][mt] = (f32x4){0.f, 0.f, 0.f, 0.f};

  const int arow  = tid >> 2;          // 0..63
  const int akoff = (tid & 3) * 8;     // 0,8,16,24

  for (int k0 = 0; k0 < E_; k0 += 32) {
    // ---- global loads into regs (issued before the barrier) ----
    const float* srcx = x + (size_t)(m0 + arow) * E_ + k0 + akoff;
    const float4 f0 = *(const float4*)srcx;
    const float4 f1 = *(const float4*)(srcx + 4);
    bf16x8 bh[6], bl[4];
    #pragma unroll
    for (int u = 0; u < 6; ++u) {      // 1536 chunks = 384 rows x 4
      const int c = u * 256 + tid;
      bh[u] = *(const bf16x8*)(whT + (size_t)(c >> 2) * E_ + k0 + (c & 3) * 8);
    }
    #pragma unroll
    for (int u = 0; u < 4; ++u) {      // 1024 chunks = 256 rows x 4
      const int c = u * 256 + tid;
      bl[u] = *(const bf16x8*)(wlT + (size_t)(c >> 2) * E_ + k0 + (c & 3) * 8);
    }
    __syncthreads();   // previous iter's frag reads done

    // ---- split x and write LDS ----
    {
      const float f[8] = {f0.x, f0.y, f0.z, f0.w, f1.x, f1.y, f1.z, f1.w};
      bf16x8 hv, lv;
      #pragma unroll
      for (int j = 0; j < 8; ++j) {
        const ushort h = bf16_rne(f[j]);
        hv[j] = (short)h;
        lv[j] = (short)bf16_rne(f[j] - bf16_tof(h));
      }
      *(bf16x8*)&AhS[arow * 40 + akoff] = hv;
      *(bf16x8*)&AlS[arow * 40 + akoff] = lv;
    }
    #pragma unroll
    for (int u = 0; u < 6; ++u) {
      const int c = u * 256 + tid;
      *(bf16x8*)&BhS[(c >> 2) * 40 + (c & 3) * 8] = bh[u];
    }
    #pragma unroll
    for (int u = 0; u < 4; ++u) {
      const int c = u * 256 + tid;
      *(bf16x8*)&BlS[(c >> 2) * 40 + (c & 3) * 8] = bl[u];
    }
    __syncthreads();

    // ---- MFMA ----
    bf16x8 a_h[4], a_l[4];
    #pragma unroll
    for (int mt = 0; mt < 4; ++mt) {
      a_h[mt] = *(const bf16x8*)&AhS[(mt * 16 + l15) * 40 + quad * 8];
      a_l[mt] = *(const bf16x8*)&AlS[(mt * 16 + l15) * 40 + quad * 8];
    }
    #pragma unroll
    for (int j = 0; j < 6; ++j) {
      const int nt   = wave + 4 * j;       // wave-uniform
      const int brow = nt * 16 + l15;
      const bf16x8 b_h = *(const bf16x8*)&BhS[brow * 40 + quad * 8];
      if (nt < 16) {                       // q,k: 3-term split
        const bf16x8 b_l = *(const bf16x8*)&BlS[brow * 40 + quad * 8];
        #pragma unroll
        for (int mt = 0; mt < 4; ++mt) {
          acc[j][mt] = mfma16(a_h[mt], b_h, acc[j][mt]);
          acc[j][mt] = mfma16(a_h[mt], b_l, acc[j][mt]);
          acc[j][mt] = mfma16(a_l[mt], b_h, acc[j][mt]);
        }
      } else {                             // v: 1-term
        #pragma unroll
        for (int mt = 0; mt < 4; ++mt)
          acc[j][mt] = mfma16(a_h[mt], b_h, acc[j][mt]);
      }
    }
  }

  // ---- epilogue: q,k split-bf16 [t][h] ----
  #pragma unroll
  for (int j = 0; j < 6; ++j) {
    const int nt = wave + 4 * j;
    if (nt < 16) {
      ushort* oh = (nt < 8) ? qh : kh;
      ushort* ol = (nt < 8) ? ql : kl;
      const int ncol = (nt & 7) * 16 + l15;
      #pragma unroll
      for (int mt = 0; mt < 4; ++mt)
        #pragma unroll
        for (int r = 0; r < 4; ++r) {
          const float a = acc[j][mt][r];
          const ushort h = bf16_rne(a);
          const size_t off = (size_t)(m0 + mt * 16 + quad * 4 + r) * H_ + ncol;
          oh[off] = h;
          ol[off] = bf16_rne(a - bf16_tof(h));
        }
    }
  }
  // ---- epilogue: v transposed to [b][h][t] via LDS ----
  __syncthreads();
  ushort* smT = BhS;                       // reuse, [128][64]
  #pragma unroll
  for (int j = 0; j < 6; ++j) {
    const int nt = wave + 4 * j;
    if (nt >= 16) {
      const int hcol = (nt - 16) * 16 + l15;
      #pragma unroll
      for (int mt = 0; mt < 4; ++mt)
        #pragma unroll
        for (int r = 0; r < 4; ++r)
          smT[hcol * 64 + mt * 16 + quad * 4 + r] = bf16_rne(acc[j][mt][r]);
    }
  }
  __syncthreads();
  const int b  = m0 >> 11;
  const int t0 = m0 & 2047;
  #pragma unroll
  for (int u = 0; u < 4; ++u) {
    const int c    = u * 256 + tid;        // 1024 chunks = 128 rows x 8
    const int n    = c >> 3;               // h 0..127
    const int toff = (c & 7) * 8;
    *(bf16x8*)(vT + ((size_t)b * H_ + n) * T_ + t0 + toff) =
        *(const bf16x8*)&smT[n * 64 + toff];
  }
}

// ---------------------------------------------------------------------------
// Kernel 2: causal flash attention, bf16-split MFMA, fp32 online softmax.
// One wave per 16 q-rows; grid (8=batch -> XCD-pinned, 128 qtiles heavy-first).
//   * 16-lane reductions via DPP row_ror (VALU) instead of __shfl_xor
//   * K fragments double-buffered in registers (1 wave/SIMD -> VGPRs free)
// ---------------------------------------------------------------------------
#define LOADK(JT, KH, KL) do {                                                \
    const ushort* khp_ = kh + base + (size_t)(JT) * 32 * H_ + quad * 8;       \
    const ushort* klp_ = kl + base + (size_t)(JT) * 32 * H_ + quad * 8;       \
    _Pragma("unroll")                                                         \
    for (int c_ = 0; c_ < 4; ++c_) {                                          \
      KH[c_*2+0] = *(const bf16x8*)(khp_ + (size_t)l15 * H_ + c_ * 32);       \
      KH[c_*2+1] = *(const bf16x8*)(khp_ + (size_t)(16 + l15) * H_ + c_ * 32);\
      KL[c_*2+0] = *(const bf16x8*)(klp_ + (size_t)l15 * H_ + c_ * 32);       \
      KL[c_*2+1] = *(const bf16x8*)(klp_ + (size_t)(16 + l15) * H_ + c_ * 32);\
    }                                                                         \
  } while (0)

#define LOADV(JT) do {                                                        \
    _Pragma("unroll")                                                         \
    for (int ct_ = 0; ct_ < 8; ++ct_)                                         \
      Vf[ct_] = *(const bf16x8*)(vT + base + (size_t)(ct_ * 16 + l15) * T_ +  \
                                 (JT) * 32 + quad * 8);                       \
  } while (0)

#define STEP(JT, KH, KL) do {                                                 \
    f32x4 shh0 = z4, shh1 = z4, sx0 = z4, sx1 = z4;                           \
    _Pragma("unroll")                                                         \
    for (int c_ = 0; c_ < 4; ++c_) {                                          \
      shh0 = mfma16(Qh[c_], KH[c_*2+0], shh0);                                \
      shh1 = mfma16(Qh[c_], KH[c_*2+1], shh1);                                \
      sx0  = mfma16(Qh[c_], KL[c_*2+0], sx0);                                 \
      sx1  = mfma16(Qh[c_], KL[c_*2+1], sx1);                                 \
      sx0  = mfma16(Ql[c_], KH[c_*2+0], sx0);                                 \
      sx1  = mfma16(Ql[c_], KH[c_*2+1], sx1);                                 \
    }                                                                         \
    float s0_[4], s1_[4];                                                     \
    _Pragma("unroll")                                                         \
    for (int r_ = 0; r_ < 4; ++r_) {                                          \
      s0_[r_] = (shh0[r_] + sx0[r_]) * SCALE_;                                \
      s1_[r_] = (shh1[r_] + sx1[r_]) * SCALE_;                                \
    }                                                                         \
    if ((JT) == ntiles - 1) {                                                 \
      const int krel0_ = (JT) * 32 + l15      - q0 - quad * 4;                \
      const int krel1_ = (JT) * 32 + 16 + l15 - q0 - quad * 4;                \
      _Pragma("unroll")                                                       \
      for (int r_ = 0; r_ < 4; ++r_) {                                        \
        if (krel0_ > r_) s0_[r_] = -1e30f;                                    \
        if (krel1_ > r_) s1_[r_] = -1e30f;                                    \
      }                                                                       \
    }                                                                         \
    float alpha_[4];                                                          \
    _Pragma("unroll")                                                         \
    for (int r_ = 0; r_ < 4; ++r_) {                                          \
      const float rm_   = rowmax16(fmaxf(s0_[r_], s1_[r_]));                  \
      const float mnew_ = fmaxf(mstate[r_], rm_);                             \
      alpha_[r_] = __expf(mstate[r_] - mnew_);                                \
      mstate[r_] = mnew_;                                                     \
      const float p0_ = __expf(s0_[r_] - mnew_);                              \
      const float p1_ = __expf(s1_[r_] - mnew_);                              \
      lstate[r_] = lstate[r_] * alpha_[r_] + rowsum16(p0_ + p1_);             \
      smP[quad * 4 + r_][l15]      = bf16_rne(p0_);                           \
      smP[quad * 4 + r_][16 + l15] = bf16_rne(p1_);                           \
    }                                                                         \
    _Pragma("unroll")                                                         \
    for (int ct_ = 0; ct_ < 8; ++ct_) {                                       \
      O[ct_][0] *= alpha_[0]; O[ct_][1] *= alpha_[1];                         \
      O[ct_][2] *= alpha_[2]; O[ct_][3] *= alpha_[3];                         \
    }                                                                         \
    const bf16x8 pA_ = *(const bf16x8*)&smP[l15][quad * 8];                   \
    _Pragma("unroll")                                                         \
    for (int ct_ = 0; ct_ < 8; ++ct_)                                         \
      O[ct_] = mfma16(pA_, Vf[ct_], O[ct_]);                                  \
  } while (0)

__global__ __launch_bounds__(64, 1) void attn_mfma(
    const ushort* __restrict__ qh, const ushort* __restrict__ ql,
    const ushort* __restrict__ kh, const ushort* __restrict__ kl,
    const ushort* __restrict__ vT, float* __restrict__ out)
{
  const int b    = blockIdx.x;
  const int qt   = (int)gridDim.y - 1 - (int)blockIdx.y;   // heavy first
  const int q0   = qt * 16;
  const int lane = threadIdx.x;
  const int quad = lane >> 4, l15 = lane & 15;
  const f32x4 z4 = (f32x4){0.f, 0.f, 0.f, 0.f};

  __shared__ __align__(16) ushort smP[16][40];

  const size_t base = (size_t)b * T_ * H_;   // == b*H_*T_ (vT base too)

  const ushort* qhp = qh + base + (size_t)(q0 + l15) * H_ + quad * 8;
  const ushort* qlp = ql + base + (size_t)(q0 + l15) * H_ + quad * 8;
  bf16x8 Qh[4], Ql[4];
  #pragma unroll
  for (int c = 0; c < 4; ++c) {
    Qh[c] = *(const bf16x8*)(qhp + c * 32);
    Ql[c] = *(const bf16x8*)(qlp + c * 32);
  }

  f32x4 O[8];
  #pragma unroll
  for (int i = 0; i < 8; ++i) O[i] = z4;
  float mstate[4] = {-1e30f, -1e30f, -1e30f, -1e30f};
  float lstate[4] = {0.f, 0.f, 0.f, 0.f};

  const int ntiles = (q0 >> 5) + 1;

  bf16x8 KhA[8], KlA[8], KhB[8], KlB[8], Vf[8];
  LOADK(0, KhA, KlA);
  int jt = 0;
  while (true) {
    LOADV(jt);
    if (jt + 1 < ntiles) LOADK(jt + 1, KhB, KlB);
    STEP(jt, KhA, KlA);
    if (++jt >= ntiles) break;
    LOADV(jt);
    if (jt + 1 < ntiles) LOADK(jt + 1, KhA, KlA);
    STEP(jt, KhB, KlB);
    if (++jt >= ntiles) break;
  }

  #pragma unroll
  for (int r = 0; r < 4; ++r) {
    const float inv = 1.0f / lstate[r];
    #pragma unroll
    for (int ct = 0; ct < 8; ++ct)
      out[base + (size_t)(q0 + quad * 4 + r) * H_ + ct * 16 + l15] = O[ct][r] * inv;
  }
}

// ---------------------------------------------------------------------------
extern "C" void kernel_launch(void* const* d_in, const int* in_sizes, int n_in,
                              void* d_out, int out_size, void* d_ws, size_t ws_size,
                              hipStream_t stream) {
  (void)in_sizes; (void)n_in; (void)out_size; (void)ws_size;
  const float* x  = (const float*)d_in[0];
  const float* Wq = (const float*)d_in[1];
  const float* Wk = (const float*)d_in[2];
  const float* Wv = (const float*)d_in[3];
  float* out = (float*)d_out;

  ushort* qhb = (ushort*)d_ws;
  ushort* qlb = qhb + (size_t)M_ * H_;
  ushort* khb = qlb + (size_t)M_ * H_;
  ushort* klb = khb + (size_t)M_ * H_;
  ushort* vTb = klb + (size_t)M_ * H_;
  ushort* whT = vTb + (size_t)M_ * H_;
  ushort* wlT = whT + (size_t)3 * H_ * E_;

  wsplit<<<dim3(192), 256, 0, stream>>>(Wq, Wk, Wv, whT, wlT);
  proj_fused<<<dim3(M_/64), 256, 0, stream>>>(x, whT, wlT,
                                              qhb, qlb, khb, klb, vTb);
  attn_mfma<<<dim3(B_, T_/16), 64, 0, stream>>>(qhb, qlb, khb, klb, vTb, out);
}

// Round 6
// 260.182 us; speedup vs baseline: 2.8435x; 1.0439x over previous
//
#include <hip/hip_runtime.h>
#include <hip/hip_bf16.h>
#include <math.h>

#define B_ 8
#define T_ 2048
#define E_ 1024
#define H_ 128
#define M_ (B_*T_)              // 16384
#define SCALE_ 45.25483399593904f   // sqrt(2048) per reference
#define SEG_ 4                      // key-range split factor for attention

typedef __attribute__((ext_vector_type(8))) short bf16x8;
typedef __attribute__((ext_vector_type(4))) float f32x4;

#define mfma16(A, Bv, C) __builtin_amdgcn_mfma_f32_16x16x32_bf16((A), (Bv), (C), 0, 0, 0)

__device__ __forceinline__ ushort bf16_rne(float f) {
  unsigned u = __float_as_uint(f);
  u += 0x7fffu + ((u >> 16) & 1u);
  return (ushort)(u >> 16);
}
__device__ __forceinline__ float bf16_tof(ushort h) {
  return __uint_as_float(((unsigned)h) << 16);
}

// DPP row_ror:N within 16-lane rows; rotate-reduce leaves the result in all
// 16 lanes. VALU-latency cross-lane (vs ~120cyc ds_permute shuffles).
template <int N>
__device__ __forceinline__ float ror16(float x) {
  return __uint_as_float((unsigned)__builtin_amdgcn_update_dpp(
      0, (int)__float_as_uint(x), 0x120 + N, 0xF, 0xF, true));
}
__device__ __forceinline__ float rowmax16(float x) {
  x = fmaxf(x, ror16<8>(x));
  x = fmaxf(x, ror16<4>(x));
  x = fmaxf(x, ror16<2>(x));
  x = fmaxf(x, ror16<1>(x));
  return x;
}
__device__ __forceinline__ float rowsum16(float x) {
  x += ror16<8>(x);
  x += ror16<4>(x);
  x += ror16<2>(x);
  x += ror16<1>(x);
  return x;
}

// ---------------------------------------------------------------------------
// Kernel 0: split W (fp32 [k][n] per matrix) -> whT/wlT bf16 [mat][n][k].
// (unchanged from round 5)
// ---------------------------------------------------------------------------
__global__ __launch_bounds__(256) void wsplit(
    const float* __restrict__ Wq, const float* __restrict__ Wk,
    const float* __restrict__ Wv,
    ushort* __restrict__ whT, ushort* __restrict__ wlT)
{
  const int idx = blockIdx.x * 256 + threadIdx.x;   // 0 .. 49151
  const int mat = idx / 16384;
  const int rem = idx % 16384;
  const int n   = rem >> 7;
  const int k0  = (rem & 127) * 8;
  const float* W = (mat == 0) ? Wq : (mat == 1) ? Wk : Wv;
  bf16x8 hv, lv;
  #pragma unroll
  for (int j = 0; j < 8; ++j) {
    const float f = W[(size_t)(k0 + j) * H_ + n];
    const ushort h = bf16_rne(f);
    hv[j] = (short)h;
    lv[j] = (short)bf16_rne(f - bf16_tof(h));
  }
  const size_t off = ((size_t)mat * H_ + n) * E_ + k0;
  *(bf16x8*)(whT + off) = hv;
  *(bf16x8*)(wlT + off) = lv;
}

// ---------------------------------------------------------------------------
// Kernel 1: FUSED QKV projection (unchanged from round 5 — passed; kept
// byte-identical so this round isolates the attention split-K change).
// ---------------------------------------------------------------------------
__global__ __launch_bounds__(256) void proj_fused(
    const float* __restrict__ x,
    const ushort* __restrict__ whT, const ushort* __restrict__ wlT,
    ushort* __restrict__ qh, ushort* __restrict__ ql,
    ushort* __restrict__ kh, ushort* __restrict__ kl,
    ushort* __restrict__ vT)
{
  const int m0  = blockIdx.x * 64;
  const int tid = threadIdx.x;
  const int wave = tid >> 6, lane = tid & 63;
  const int quad = lane >> 4, l15 = lane & 15;

  __shared__ __align__(16) ushort AhS[64 * 40];
  __shared__ __align__(16) ushort AlS[64 * 40];
  __shared__ __align__(16) ushort BhS[384 * 40];
  __shared__ __align__(16) ushort BlS[256 * 40];

  f32x4 acc[6][4];
  #pragma unroll
  for (int j = 0; j < 6; ++j)
    #pragma unroll
    for (int mt = 0; mt < 4; ++mt) acc[j][mt] = (f32x4){0.f, 0.f, 0.f, 0.f};

  const int arow  = tid >> 2;
  const int akoff = (tid & 3) * 8;

  for (int k0 = 0; k0 < E_; k0 += 32) {
    const float* srcx = x + (size_t)(m0 + arow) * E_ + k0 + akoff;
    const float4 f0 = *(const float4*)srcx;
    const float4 f1 = *(const float4*)(srcx + 4);
    bf16x8 bh[6], bl[4];
    #pragma unroll
    for (int u = 0; u < 6; ++u) {      // 1536 chunks = 384 rows x 4
      const int c = u * 256 + tid;
      bh[u] = *(const bf16x8*)(whT + (size_t)(c >> 2) * E_ + k0 + (c & 3) * 8);
    }
    #pragma unroll
    for (int u = 0; u < 4; ++u) {      // 1024 chunks = 256 rows x 4
      const int c = u * 256 + tid;
      bl[u] = *(const bf16x8*)(wlT + (size_t)(c >> 2) * E_ + k0 + (c & 3) * 8);
    }
    __syncthreads();

    {
      const float f[8] = {f0.x, f0.y, f0.z, f0.w, f1.x, f1.y, f1.z, f1.w};
      bf16x8 hv, lv;
      #pragma unroll
      for (int j = 0; j < 8; ++j) {
        const ushort h = bf16_rne(f[j]);
        hv[j] = (short)h;
        lv[j] = (short)bf16_rne(f[j] - bf16_tof(h));
      }
      *(bf16x8*)&AhS[arow * 40 + akoff] = hv;
      *(bf16x8*)&AlS[arow * 40 + akoff] = lv;
    }
    #pragma unroll
    for (int u = 0; u < 6; ++u) {
      const int c = u * 256 + tid;
      *(bf16x8*)&BhS[(c >> 2) * 40 + (c & 3) * 8] = bh[u];
    }
    #pragma unroll
    for (int u = 0; u < 4; ++u) {
      const int c = u * 256 + tid;
      *(bf16x8*)&BlS[(c >> 2) * 40 + (c & 3) * 8] = bl[u];
    }
    __syncthreads();

    bf16x8 a_h[4], a_l[4];
    #pragma unroll
    for (int mt = 0; mt < 4; ++mt) {
      a_h[mt] = *(const bf16x8*)&AhS[(mt * 16 + l15) * 40 + quad * 8];
      a_l[mt] = *(const bf16x8*)&AlS[(mt * 16 + l15) * 40 + quad * 8];
    }
    #pragma unroll
    for (int j = 0; j < 6; ++j) {
      const int nt   = wave + 4 * j;
      const int brow = nt * 16 + l15;
      const bf16x8 b_h = *(const bf16x8*)&BhS[brow * 40 + quad * 8];
      if (nt < 16) {
        const bf16x8 b_l = *(const bf16x8*)&BlS[brow * 40 + quad * 8];
        #pragma unroll
        for (int mt = 0; mt < 4; ++mt) {
          acc[j][mt] = mfma16(a_h[mt], b_h, acc[j][mt]);
          acc[j][mt] = mfma16(a_h[mt], b_l, acc[j][mt]);
          acc[j][mt] = mfma16(a_l[mt], b_h, acc[j][mt]);
        }
      } else {
        #pragma unroll
        for (int mt = 0; mt < 4; ++mt)
          acc[j][mt] = mfma16(a_h[mt], b_h, acc[j][mt]);
      }
    }
  }

  #pragma unroll
  for (int j = 0; j < 6; ++j) {
    const int nt = wave + 4 * j;
    if (nt < 16) {
      ushort* oh = (nt < 8) ? qh : kh;
      ushort* ol = (nt < 8) ? ql : kl;
      const int ncol = (nt & 7) * 16 + l15;
      #pragma unroll
      for (int mt = 0; mt < 4; ++mt)
        #pragma unroll
        for (int r = 0; r < 4; ++r) {
          const float a = acc[j][mt][r];
          const ushort h = bf16_rne(a);
          const size_t off = (size_t)(m0 + mt * 16 + quad * 4 + r) * H_ + ncol;
          oh[off] = h;
          ol[off] = bf16_rne(a - bf16_tof(h));
        }
    }
  }
  __syncthreads();
  ushort* smT = BhS;                       // reuse, [128][64]
  #pragma unroll
  for (int j = 0; j < 6; ++j) {
    const int nt = wave + 4 * j;
    if (nt >= 16) {
      const int hcol = (nt - 16) * 16 + l15;
      #pragma unroll
      for (int mt = 0; mt < 4; ++mt)
        #pragma unroll
        for (int r = 0; r < 4; ++r)
          smT[hcol * 64 + mt * 16 + quad * 4 + r] = bf16_rne(acc[j][mt][r]);
    }
  }
  __syncthreads();
  const int b  = m0 >> 11;
  const int t0 = m0 & 2047;
  #pragma unroll
  for (int u = 0; u < 4; ++u) {
    const int c    = u * 256 + tid;        // 1024 chunks = 128 rows x 8
    const int n    = c >> 3;
    const int toff = (c & 7) * 8;
    *(bf16x8*)(vT + ((size_t)b * H_ + n) * T_ + t0 + toff) =
        *(const bf16x8*)&smT[n * 64 + toff];
  }
}

// ---------------------------------------------------------------------------
// Kernel 2: causal flash attention, SPLIT-K over the key range.
// grid (32 = b*4+seg, 128 = qtile reversed), 1 wave/block -> 4096 waves
// (~3/SIMD resident; round-5's 1024 waves = 1/SIMD was the occupancy wall,
// 80% memory-stall). Each wave covers key-tiles [seg*c, min((seg+1)*c, n)),
// c = ceil(n/4), and writes UNNORMALIZED partial O (bf16) + (m,l) fp32.
// Empty segments write zeroed partials (ws is poisoned each launch).
// Single K register buffer; V loaded after the QK chain so it reuses dead
// K registers (~160 VGPR target for 3 waves/SIMD). DPP reductions kept.
// ---------------------------------------------------------------------------
__global__ __launch_bounds__(64) void attn_split(
    const ushort* __restrict__ qh, const ushort* __restrict__ ql,
    const ushort* __restrict__ kh, const ushort* __restrict__ kl,
    const ushort* __restrict__ vT,
    ushort* __restrict__ Opart, float* __restrict__ mlpart)
{
  const int b    = (int)blockIdx.x >> 2;
  const int seg  = (int)blockIdx.x & 3;
  const int qt   = 127 - (int)blockIdx.y;    // heavy first
  const int q0   = qt * 16;
  const int lane = threadIdx.x;
  const int quad = lane >> 4, l15 = lane & 15;
  const f32x4 z4 = (f32x4){0.f, 0.f, 0.f, 0.f};

  __shared__ __align__(16) ushort smP[16][40];

  const int ntiles = (q0 >> 5) + 1;            // global key-tile count
  const int cnt    = (ntiles + 3) >> 2;        // tiles per segment
  const int jt0    = seg * cnt;
  const int jt1    = (jt0 + cnt < ntiles) ? (jt0 + cnt) : ntiles;

  const size_t pidx = ((size_t)(b * 128 + qt)) * SEG_ + seg;
  ushort* op = Opart + pidx * 2048;            // [16 rows][128 cols]
  float*  ml = mlpart + pidx * 32;             // [16 rows][m,l]

  if (jt0 >= jt1) {                            // empty segment: zero partial
    const bf16x8 zz = {0, 0, 0, 0, 0, 0, 0, 0};
    #pragma unroll
    for (int u = 0; u < 4; ++u)                // 64 lanes x 4 x 8 = 2048
      *(bf16x8*)(op + lane * 32 + u * 8) = zz;
    if (lane < 32) ml[lane] = (lane & 1) ? 0.f : -1e30f;
    return;
  }

  const size_t base = (size_t)b * T_ * H_;

  const ushort* qhp = qh + base + (size_t)(q0 + l15) * H_ + quad * 8;
  const ushort* qlp = ql + base + (size_t)(q0 + l15) * H_ + quad * 8;
  bf16x8 Qh[4], Ql[4];
  #pragma unroll
  for (int c = 0; c < 4; ++c) {
    Qh[c] = *(const bf16x8*)(qhp + c * 32);
    Ql[c] = *(const bf16x8*)(qlp + c * 32);
  }

  f32x4 O[8];
  #pragma unroll
  for (int i = 0; i < 8; ++i) O[i] = z4;
  float mstate[4] = {-1e30f, -1e30f, -1e30f, -1e30f};
  float lstate[4] = {0.f, 0.f, 0.f, 0.f};

  for (int jt = jt0; jt < jt1; ++jt) {
    const int k0 = jt * 32;
    const ushort* khp = kh + base + (size_t)k0 * H_ + quad * 8;
    const ushort* klp = kl + base + (size_t)k0 * H_ + quad * 8;

    bf16x8 Kh[8], Kl[8];
    #pragma unroll
    for (int c = 0; c < 4; ++c) {
      Kh[c*2+0] = *(const bf16x8*)(khp + (size_t)l15 * H_ + c * 32);
      Kh[c*2+1] = *(const bf16x8*)(khp + (size_t)(16 + l15) * H_ + c * 32);
      Kl[c*2+0] = *(const bf16x8*)(klp + (size_t)l15 * H_ + c * 32);
      Kl[c*2+1] = *(const bf16x8*)(klp + (size_t)(16 + l15) * H_ + c * 32);
    }

    // S = Q K^T (3-term split)
    f32x4 shh0 = z4, shh1 = z4, sx0 = z4, sx1 = z4;
    #pragma unroll
    for (int c = 0; c < 4; ++c) {
      shh0 = mfma16(Qh[c], Kh[c*2+0], shh0);
      shh1 = mfma16(Qh[c], Kh[c*2+1], shh1);
      sx0  = mfma16(Qh[c], Kl[c*2+0], sx0);
      sx1  = mfma16(Qh[c], Kl[c*2+1], sx1);
      sx0  = mfma16(Ql[c], Kh[c*2+0], sx0);
      sx1  = mfma16(Ql[c], Kh[c*2+1], sx1);
    }

    // V loads issued after QK chain (reuses dead K registers; latency
    // hides under the softmax VALU chain)
    bf16x8 Vf[8];
    #pragma unroll
    for (int ct = 0; ct < 8; ++ct)
      Vf[ct] = *(const bf16x8*)(vT + base + (size_t)(ct * 16 + l15) * T_ +
                                k0 + quad * 8);

    float s0[4], s1[4];
    #pragma unroll
    for (int r = 0; r < 4; ++r) {
      s0[r] = (shh0[r] + sx0[r]) * SCALE_;
      s1[r] = (shh1[r] + sx1[r]) * SCALE_;
    }
    if (jt == ntiles - 1) {   // only the globally-last tile has masked keys
      const int krel0 = k0 + l15      - q0 - quad * 4;
      const int krel1 = k0 + 16 + l15 - q0 - quad * 4;
      #pragma unroll
      for (int r = 0; r < 4; ++r) {
        if (krel0 > r) s0[r] = -1e30f;
        if (krel1 > r) s1[r] = -1e30f;
      }
    }

    float alpha[4];
    #pragma unroll
    for (int r = 0; r < 4; ++r) {
      const float rm   = rowmax16(fmaxf(s0[r], s1[r]));
      const float mnew = fmaxf(mstate[r], rm);
      alpha[r] = __expf(mstate[r] - mnew);
      mstate[r] = mnew;
      const float p0 = __expf(s0[r] - mnew);
      const float p1 = __expf(s1[r] - mnew);
      lstate[r] = lstate[r] * alpha[r] + rowsum16(p0 + p1);
      smP[quad * 4 + r][l15]      = bf16_rne(p0);
      smP[quad * 4 + r][16 + l15] = bf16_rne(p1);
    }
    #pragma unroll
    for (int ct = 0; ct < 8; ++ct) {
      O[ct][0] *= alpha[0]; O[ct][1] *= alpha[1];
      O[ct][2] *= alpha[2]; O[ct][3] *= alpha[3];
    }
    const bf16x8 pA = *(const bf16x8*)&smP[l15][quad * 8];
    #pragma unroll
    for (int ct = 0; ct < 8; ++ct)
      O[ct] = mfma16(pA, Vf[ct], O[ct]);
  }

  // write UNNORMALIZED partial O (bf16) + m,l (fp32)
  #pragma unroll
  for (int r = 0; r < 4; ++r)
    #pragma unroll
    for (int ct = 0; ct < 8; ++ct)
      op[(quad * 4 + r) * 128 + ct * 16 + l15] = bf16_rne(O[ct][r]);
  if (l15 == 0) {
    #pragma unroll
    for (int r = 0; r < 4; ++r) {
      ml[(quad * 4 + r) * 2]     = mstate[r];
      ml[(quad * 4 + r) * 2 + 1] = lstate[r];
    }
  }
}

// ---------------------------------------------------------------------------
// Kernel 3: combine 4 split-K partials per q-row.
// O = sum_s O_s e^{m_s - M} / (sum_s l_s e^{m_s - M}).  2048 blocks x 256.
// ---------------------------------------------------------------------------
__global__ __launch_bounds__(256) void attn_combine(
    const ushort* __restrict__ Opart, const float* __restrict__ mlpart,
    float* __restrict__ out)
{
  const int idx = blockIdx.x * 256 + threadIdx.x;   // 0..524287
  const int c4  = idx & 31;                         // col-quad 0..31
  const int r   = idx >> 5;                         // row 0..16383
  const int t   = r & 2047;
  const int qt  = t >> 4, r16 = t & 15;
  const size_t pb = ((size_t)((r >> 11) * 128 + qt)) * SEG_;

  float m[SEG_], l[SEG_];
  #pragma unroll
  for (int s = 0; s < SEG_; ++s) {
    m[s] = mlpart[(pb + s) * 32 + r16 * 2];
    l[s] = mlpart[(pb + s) * 32 + r16 * 2 + 1];
  }
  float M = m[0];
  #pragma unroll
  for (int s = 1; s < SEG_; ++s) M = fmaxf(M, m[s]);
  float w[SEG_], L = 0.f;
  #pragma unroll
  for (int s = 0; s < SEG_; ++s) {
    w[s] = __expf(m[s] - M);       // m=-1e30 (empty/losing seg) -> 0
    L += l[s] * w[s];
  }
  float4 acc = make_float4(0.f, 0.f, 0.f, 0.f);
  #pragma unroll
  for (int s = 0; s < SEG_; ++s) {
    const ushort4 o = *(const ushort4*)(Opart + (pb + s) * 2048 + r16 * 128 + c4 * 4);
    acc.x += w[s] * bf16_tof(o.x);
    acc.y += w[s] * bf16_tof(o.y);
    acc.z += w[s] * bf16_tof(o.z);
    acc.w += w[s] * bf16_tof(o.w);
  }
  const float inv = 1.0f / L;
  *(float4*)(out + (size_t)r * H_ + c4 * 4) =
      make_float4(acc.x * inv, acc.y * inv, acc.z * inv, acc.w * inv);
}

// ---------------------------------------------------------------------------
extern "C" void kernel_launch(void* const* d_in, const int* in_sizes, int n_in,
                              void* d_out, int out_size, void* d_ws, size_t ws_size,
                              hipStream_t stream) {
  (void)in_sizes; (void)n_in; (void)out_size; (void)ws_size;
  const float* x  = (const float*)d_in[0];
  const float* Wq = (const float*)d_in[1];
  const float* Wk = (const float*)d_in[2];
  const float* Wv = (const float*)d_in[3];
  float* out = (float*)d_out;

  // ws layout (ushort elems unless noted):
  //   qh,ql,kh,kl,vT : 5 x M_*H_            = 10,485,760
  //   whT, wlT       : 2 x 3*H_*E_          =    786,432
  //   Opart          : 8*128*4*2048         =  8,388,608   (16.8 MB bf16)
  //   mlpart (float) : 8*128*4*16*2 floats  =    131,072 f (0.5 MB)
  // total ~39.9 MB
  ushort* qhb = (ushort*)d_ws;
  ushort* qlb = qhb + (size_t)M_ * H_;
  ushort* khb = qlb + (size_t)M_ * H_;
  ushort* klb = khb + (size_t)M_ * H_;
  ushort* vTb = klb + (size_t)M_ * H_;
  ushort* whT = vTb + (size_t)M_ * H_;
  ushort* wlT = whT + (size_t)3 * H_ * E_;
  ushort* Opart = wlT + (size_t)3 * H_ * E_;
  float*  mlpart = (float*)(Opart + (size_t)B_ * 128 * SEG_ * 2048);

  wsplit<<<dim3(192), 256, 0, stream>>>(Wq, Wk, Wv, whT, wlT);
  proj_fused<<<dim3(M_/64), 256, 0, stream>>>(x, whT, wlT,
                                              qhb, qlb, khb, klb, vTb);
  attn_split<<<dim3(32, 128), 64, 0, stream>>>(qhb, qlb, khb, klb, vTb,
                                               Opart, mlpart);
  attn_combine<<<dim3(2048), 256, 0, stream>>>(Opart, mlpart, out);
}

// Round 7
// 186.243 us; speedup vs baseline: 3.9723x; 1.3970x over previous
//
#include <hip/hip_runtime.h>
#include <hip/hip_bf16.h>
#include <math.h>

#define B_ 8
#define T_ 2048
#define E_ 1024
#define H_ 128
#define M_ (B_*T_)              // 16384
#define SCALE_ 45.25483399593904f   // sqrt(2048) per reference
#define SEG_ 4                      // key-range split factor for attention

typedef __attribute__((ext_vector_type(8))) short bf16x8;
typedef __attribute__((ext_vector_type(4))) float f32x4;

#define mfma16(A, Bv, C) __builtin_amdgcn_mfma_f32_16x16x32_bf16((A), (Bv), (C), 0, 0, 0)

__device__ __forceinline__ ushort bf16_rne(float f) {
  unsigned u = __float_as_uint(f);
  u += 0x7fffu + ((u >> 16) & 1u);
  return (ushort)(u >> 16);
}
__device__ __forceinline__ float bf16_tof(ushort h) {
  return __uint_as_float(((unsigned)h) << 16);
}

// DPP row_ror:N within 16-lane rows; rotate-reduce leaves result in all lanes.
template <int N>
__device__ __forceinline__ float ror16(float x) {
  return __uint_as_float((unsigned)__builtin_amdgcn_update_dpp(
      0, (int)__float_as_uint(x), 0x120 + N, 0xF, 0xF, true));
}
__device__ __forceinline__ float rowmax16(float x) {
  x = fmaxf(x, ror16<8>(x));
  x = fmaxf(x, ror16<4>(x));
  x = fmaxf(x, ror16<2>(x));
  x = fmaxf(x, ror16<1>(x));
  return x;
}
__device__ __forceinline__ float rowsum16(float x) {
  x += ror16<8>(x);
  x += ror16<4>(x);
  x += ror16<2>(x);
  x += ror16<1>(x);
  return x;
}

// ---------------------------------------------------------------------------
// Kernel 0: split W (fp32 [k][n] per matrix) -> whT/wlT bf16 [mat][n][k].
// (unchanged — passing since r3)
// ---------------------------------------------------------------------------
__global__ __launch_bounds__(256) void wsplit(
    const float* __restrict__ Wq, const float* __restrict__ Wk,
    const float* __restrict__ Wv,
    ushort* __restrict__ whT, ushort* __restrict__ wlT)
{
  const int idx = blockIdx.x * 256 + threadIdx.x;   // 0 .. 49151
  const int mat = idx / 16384;
  const int rem = idx % 16384;
  const int n   = rem >> 7;
  const int k0  = (rem & 127) * 8;
  const float* W = (mat == 0) ? Wq : (mat == 1) ? Wk : Wv;
  bf16x8 hv, lv;
  #pragma unroll
  for (int j = 0; j < 8; ++j) {
    const float f = W[(size_t)(k0 + j) * H_ + n];
    const ushort h = bf16_rne(f);
    hv[j] = (short)h;
    lv[j] = (short)bf16_rne(f - bf16_tof(h));
  }
  const size_t off = ((size_t)mat * H_ + n) * E_ + k0;
  *(bf16x8*)(whT + off) = hv;
  *(bf16x8*)(wlT + off) = lv;
}

// ---------------------------------------------------------------------------
// Kernel 1: QKV projection, round-7: split into 2 n-halves (grid 512 -> 2
// blocks/CU; was 256 blocks = 1/CU, latency-exposed) and k-loop restructured
// to sync; write LDS; sync; prefetch-next; compute (staging latency hidden
// under MFMA). Block = 64 m-rows x 192 n-cols (half h: cols h*192..+191 of
// q|k|v). q,k 3-term split MFMA; v 1-term.
// Chunk audit: Bh 192r x 4 = 768 (u<3); Bl half0 768 / half1 256 (guard).
// ---------------------------------------------------------------------------
__global__ __launch_bounds__(256) void proj_fused(
    const float* __restrict__ x,
    const ushort* __restrict__ whT, const ushort* __restrict__ wlT,
    ushort* __restrict__ qh, ushort* __restrict__ ql,
    ushort* __restrict__ kh, ushort* __restrict__ kl,
    ushort* __restrict__ vT)
{
  const int m0   = blockIdx.x * 64;
  const int half = blockIdx.y;
  const int tid  = threadIdx.x;
  const int wave = tid >> 6, lane = tid & 63;
  const int quad = lane >> 4, l15 = lane & 15;

  __shared__ __align__(16) ushort SM[20480];   // 40 KB
  ushort* AhS = SM;            // [64][40]
  ushort* AlS = SM + 2560;     // [64][40]
  ushort* BhS = SM + 5120;     // [192][40]
  ushort* BlS = SM + 12800;    // [192][40] (used rows: half0 192, half1 64)

  const int nlc = (half == 0) ? 768 : 256;     // Bl chunks this half

  f32x4 acc[3][4];
  #pragma unroll
  for (int j = 0; j < 3; ++j)
    #pragma unroll
    for (int mt = 0; mt < 4; ++mt) acc[j][mt] = (f32x4){0.f, 0.f, 0.f, 0.f};

  const int arow  = tid >> 2;          // 0..63
  const int akoff = (tid & 3) * 8;     // 0,8,16,24

  // ---- prologue: stage k0=0 into regs ----
  float4 f0, f1;
  bf16x8 bh[3], bl[3];
  {
    const float* srcx = x + (size_t)(m0 + arow) * E_ + akoff;
    f0 = *(const float4*)srcx;
    f1 = *(const float4*)(srcx + 4);
    #pragma unroll
    for (int u = 0; u < 3; ++u) {
      const int c = u * 256 + tid;
      bh[u] = *(const bf16x8*)(whT + (size_t)(half*192 + (c >> 2)) * E_ + (c & 3) * 8);
      if (c < nlc)
        bl[u] = *(const bf16x8*)(wlT + (size_t)(half*192 + (c >> 2)) * E_ + (c & 3) * 8);
    }
  }

  for (int k0 = 0; k0 < E_; k0 += 32) {
    __syncthreads();   // previous iter's frag reads done

    // ---- write staged regs to LDS (split x on the fly) ----
    {
      const float f[8] = {f0.x, f0.y, f0.z, f0.w, f1.x, f1.y, f1.z, f1.w};
      bf16x8 hv, lv;
      #pragma unroll
      for (int j = 0; j < 8; ++j) {
        const ushort h = bf16_rne(f[j]);
        hv[j] = (short)h;
        lv[j] = (short)bf16_rne(f[j] - bf16_tof(h));
      }
      *(bf16x8*)&AhS[arow * 40 + akoff] = hv;
      *(bf16x8*)&AlS[arow * 40 + akoff] = lv;
    }
    #pragma unroll
    for (int u = 0; u < 3; ++u) {
      const int c = u * 256 + tid;
      *(bf16x8*)&BhS[(c >> 2) * 40 + (c & 3) * 8] = bh[u];
      if (c < nlc)
        *(bf16x8*)&BlS[(c >> 2) * 40 + (c & 3) * 8] = bl[u];
    }
    __syncthreads();

    // ---- prefetch next k-tile into regs (latency hides under MFMA) ----
    if (k0 + 32 < E_) {
      const int kn = k0 + 32;
      const float* srcx = x + (size_t)(m0 + arow) * E_ + kn + akoff;
      f0 = *(const float4*)srcx;
      f1 = *(const float4*)(srcx + 4);
      #pragma unroll
      for (int u = 0; u < 3; ++u) {
        const int c = u * 256 + tid;
        bh[u] = *(const bf16x8*)(whT + (size_t)(half*192 + (c >> 2)) * E_ + kn + (c & 3) * 8);
        if (c < nlc)
          bl[u] = *(const bf16x8*)(wlT + (size_t)(half*192 + (c >> 2)) * E_ + kn + (c & 3) * 8);
      }
    }

    // ---- MFMA ----
    bf16x8 a_h[4], a_l[4];
    #pragma unroll
    for (int mt = 0; mt < 4; ++mt) {
      a_h[mt] = *(const bf16x8*)&AhS[(mt * 16 + l15) * 40 + quad * 8];
      a_l[mt] = *(const bf16x8*)&AlS[(mt * 16 + l15) * 40 + quad * 8];
    }
    #pragma unroll
    for (int j = 0; j < 3; ++j) {
      const int ntl = wave + 4 * j;            // local tile 0..11
      const int g   = half * 12 + ntl;         // global tile 0..23
      const bf16x8 b_h = *(const bf16x8*)&BhS[(ntl * 16 + l15) * 40 + quad * 8];
      if (g < 16) {                            // q,k: 3-term split
        const bf16x8 b_l = *(const bf16x8*)&BlS[(ntl * 16 + l15) * 40 + quad * 8];
        #pragma unroll
        for (int mt = 0; mt < 4; ++mt) {
          acc[j][mt] = mfma16(a_h[mt], b_h, acc[j][mt]);
          acc[j][mt] = mfma16(a_h[mt], b_l, acc[j][mt]);
          acc[j][mt] = mfma16(a_l[mt], b_h, acc[j][mt]);
        }
      } else {                                 // v: 1-term
        #pragma unroll
        for (int mt = 0; mt < 4; ++mt)
          acc[j][mt] = mfma16(a_h[mt], b_h, acc[j][mt]);
      }
    }
  }

  // ---- epilogue: q,k split-bf16 [t][h] ----
  #pragma unroll
  for (int j = 0; j < 3; ++j) {
    const int g = half * 12 + wave + 4 * j;
    if (g < 16) {
      ushort* oh = (g < 8) ? qh : kh;
      ushort* ol = (g < 8) ? ql : kl;
      const int ncol = (g & 7) * 16 + l15;
      #pragma unroll
      for (int mt = 0; mt < 4; ++mt)
        #pragma unroll
        for (int r = 0; r < 4; ++r) {
          const float a = acc[j][mt][r];
          const ushort h = bf16_rne(a);
          const size_t off = (size_t)(m0 + mt * 16 + quad * 4 + r) * H_ + ncol;
          oh[off] = h;
          ol[off] = bf16_rne(a - bf16_tof(h));
        }
    }
  }
  // ---- epilogue: v (half 1 only) transposed to [b][h][t] via LDS ----
  if (half == 1) {
    __syncthreads();
    ushort* smT = SM;                          // [128][64] = 8192 ush
    #pragma unroll
    for (int j = 1; j < 3; ++j) {              // g = 16+w, 20+w are the v tiles
      const int g = 12 + wave + 4 * j;
      const int hcol = (g - 16) * 16 + l15;
      #pragma unroll
      for (int mt = 0; mt < 4; ++mt)
        #pragma unroll
        for (int r = 0; r < 4; ++r)
          smT[hcol * 64 + mt * 16 + quad * 4 + r] = bf16_rne(acc[j][mt][r]);
    }
    __syncthreads();
    const int b  = m0 >> 11;
    const int t0 = m0 & 2047;
    #pragma unroll
    for (int u = 0; u < 4; ++u) {
      const int c    = u * 256 + tid;          // 1024 chunks = 128 rows x 8
      const int n    = c >> 3;
      const int toff = (c & 7) * 8;
      *(bf16x8*)(vT + ((size_t)b * H_ + n) * T_ + t0 + toff) =
          *(const bf16x8*)&smT[n * 64 + toff];
    }
  }
}

// ---------------------------------------------------------------------------
// Kernel 2: block-level flash attention with split-K. Round-7 redesign:
//  * 256-thr blocks, Q-tile 64 (wave w: rows q0+w*16..+15): K-hi/lo + V
//    staged in LDS ONCE per key-tile, shared by 4 waves -> 4x less global
//    K/V traffic (r6: every wave streamed 24 KB/iter privately -> L3-bound).
//  * XCD pinning: grid.x = seg*8+b -> x%8 = b; one batch per XCD; its
//    q/k/v set (~2.5 MB) fits the 4 MB XCD L2 -> L2-hit steady state.
//  * k-loop: sync; write LDS; sync; prefetch-next->regs; compute.
//  * per-wave tile skip (jt < ntiles_w) avoids fully-masked-tile poison
//    (all-masked tile with m=-1e30 would give exp(0)=1 garbage); barriers
//    stay block-uniform. Mask applied at wave's own diagonal tile.
// LDS 32.3 KB; grid (32, 32) = 1024 blocks = 4/CU nominal.
// ---------------------------------------------------------------------------
__global__ __launch_bounds__(256) void attn_flash(
    const ushort* __restrict__ qh, const ushort* __restrict__ ql,
    const ushort* __restrict__ kh, const ushort* __restrict__ kl,
    const ushort* __restrict__ vT,
    ushort* __restrict__ Opart, float* __restrict__ mlpart)
{
  const int b    = (int)blockIdx.x & 7;        // %8 -> XCD pin
  const int seg  = (int)blockIdx.x >> 3;
  const int qt   = 31 - (int)blockIdx.y;       // heavy first
  const int q0   = qt * 64;
  const int tid  = threadIdx.x;
  const int wave = tid >> 6, lane = tid & 63;
  const int quad = lane >> 4, l15 = lane & 15;
  const f32x4 z4 = (f32x4){0.f, 0.f, 0.f, 0.f};

  __shared__ __align__(16) ushort KhS[32 * 132];   // [key][h] pad 132
  __shared__ __align__(16) ushort KlS[32 * 132];
  __shared__ __align__(16) ushort VtS[128 * 40];   // [h][key] pad 40
  __shared__ __align__(16) ushort smP[4 * 640];    // per-wave 16x40

  const int ntiles = 2 * qt + 2;               // block key-tiles (32 keys)
  const int cnt    = (ntiles + SEG_ - 1) >> 2;
  const int jt0    = seg * cnt;
  const int jt1    = (jt0 + cnt < ntiles) ? (jt0 + cnt) : ntiles;

  const int q0w  = q0 + wave * 16;             // this wave's rows
  const int ntw  = ((q0w + 15) >> 5) + 1;      // wave's own tile count
  const size_t pidx = ((size_t)(b * 128 + qt * 4 + wave)) * SEG_ + seg;
  ushort* op = Opart + pidx * 2048;
  float*  ml = mlpart + pidx * 32;

  if (jt0 >= jt1) {                            // whole block empty
    const bf16x8 zz = {0, 0, 0, 0, 0, 0, 0, 0};
    #pragma unroll
    for (int u = 0; u < 4; ++u)
      *(bf16x8*)(op + lane * 32 + u * 8) = zz;
    if (lane < 32) ml[lane] = (lane & 1) ? 0.f : -1e30f;
    return;
  }

  const size_t base = (size_t)b * T_ * H_;

  const ushort* qhp = qh + base + (size_t)(q0w + l15) * H_ + quad * 8;
  const ushort* qlp = ql + base + (size_t)(q0w + l15) * H_ + quad * 8;
  bf16x8 Qh[4], Ql[4];
  #pragma unroll
  for (int c = 0; c < 4; ++c) {
    Qh[c] = *(const bf16x8*)(qhp + c * 32);
    Ql[c] = *(const bf16x8*)(qlp + c * 32);
  }

  f32x4 O[8];
  #pragma unroll
  for (int i = 0; i < 8; ++i) O[i] = z4;
  float mstate[4] = {-1e30f, -1e30f, -1e30f, -1e30f};
  float lstate[4] = {0.f, 0.f, 0.f, 0.f};

  // staging regs: Kh 2, Kl 2, V 2 chunks of 16 B per thread
  bf16x8 rkh[2], rkl[2], rv[2];
  {
    const int k0 = jt0 * 32;
    #pragma unroll
    for (int u = 0; u < 2; ++u) {
      const int c = u * 256 + tid;             // 512 chunks = 32 rows x 16
      rkh[u] = *(const bf16x8*)(kh + base + (size_t)(k0 + (c >> 4)) * H_ + (c & 15) * 8);
      rkl[u] = *(const bf16x8*)(kl + base + (size_t)(k0 + (c >> 4)) * H_ + (c & 15) * 8);
      rv[u]  = *(const bf16x8*)(vT + base + (size_t)(c >> 2) * T_ + k0 + (c & 3) * 8);
    }                                          // V: 512 chunks = 128 rows x 4
  }

  for (int jt = jt0; jt < jt1; ++jt) {
    __syncthreads();   // prev iter's LDS reads done
    #pragma unroll
    for (int u = 0; u < 2; ++u) {
      const int c = u * 256 + tid;
      *(bf16x8*)&KhS[(c >> 4) * 132 + (c & 15) * 8] = rkh[u];
      *(bf16x8*)&KlS[(c >> 4) * 132 + (c & 15) * 8] = rkl[u];
      *(bf16x8*)&VtS[(c >> 2) * 40  + (c & 3) * 8]  = rv[u];
    }
    __syncthreads();   // LDS ready

    if (jt + 1 < jt1) {                        // prefetch next tile
      const int kn = (jt + 1) * 32;
      #pragma unroll
      for (int u = 0; u < 2; ++u) {
        const int c = u * 256 + tid;
        rkh[u] = *(const bf16x8*)(kh + base + (size_t)(kn + (c >> 4)) * H_ + (c & 15) * 8);
        rkl[u] = *(const bf16x8*)(kl + base + (size_t)(kn + (c >> 4)) * H_ + (c & 15) * 8);
        rv[u]  = *(const bf16x8*)(vT + base + (size_t)(c >> 2) * T_ + kn + (c & 3) * 8);
      }
    }

    if (jt < ntw) {                            // wave-uniform skip
      const int k0 = jt * 32;
      // S = Q K^T from LDS (3-term split)
      f32x4 shh0 = z4, shh1 = z4, sx0 = z4, sx1 = z4;
      #pragma unroll
      for (int c = 0; c < 4; ++c) {
        const bf16x8 kh0 = *(const bf16x8*)&KhS[l15 * 132 + c * 32 + quad * 8];
        const bf16x8 kh1 = *(const bf16x8*)&KhS[(16 + l15) * 132 + c * 32 + quad * 8];
        const bf16x8 kl0 = *(const bf16x8*)&KlS[l15 * 132 + c * 32 + quad * 8];
        const bf16x8 kl1 = *(const bf16x8*)&KlS[(16 + l15) * 132 + c * 32 + quad * 8];
        shh0 = mfma16(Qh[c], kh0, shh0);
        shh1 = mfma16(Qh[c], kh1, shh1);
        sx0  = mfma16(Qh[c], kl0, sx0);
        sx1  = mfma16(Qh[c], kl1, sx1);
        sx0  = mfma16(Ql[c], kh0, sx0);
        sx1  = mfma16(Ql[c], kh1, sx1);
      }

      float s0[4], s1[4];
      #pragma unroll
      for (int r = 0; r < 4; ++r) {
        s0[r] = (shh0[r] + sx0[r]) * SCALE_;
        s1[r] = (shh1[r] + sx1[r]) * SCALE_;
      }
      if (jt == ntw - 1) {                     // wave's diagonal tile
        const int krel0 = k0 + l15      - q0w - quad * 4;
        const int krel1 = k0 + 16 + l15 - q0w - quad * 4;
        #pragma unroll
        for (int r = 0; r < 4; ++r) {
          if (krel0 > r) s0[r] = -1e30f;
          if (krel1 > r) s1[r] = -1e30f;
        }
      }

      float alpha[4];
      #pragma unroll
      for (int r = 0; r < 4; ++r) {
        const float rm   = rowmax16(fmaxf(s0[r], s1[r]));
        const float mnew = fmaxf(mstate[r], rm);
        alpha[r] = __expf(mstate[r] - mnew);
        mstate[r] = mnew;
        const float p0 = __expf(s0[r] - mnew);
        const float p1 = __expf(s1[r] - mnew);
        lstate[r] = lstate[r] * alpha[r] + rowsum16(p0 + p1);
        smP[wave * 640 + (quad * 4 + r) * 40 + l15]      = bf16_rne(p0);
        smP[wave * 640 + (quad * 4 + r) * 40 + 16 + l15] = bf16_rne(p1);
      }
      #pragma unroll
      for (int ct = 0; ct < 8; ++ct) {
        O[ct][0] *= alpha[0]; O[ct][1] *= alpha[1];
        O[ct][2] *= alpha[2]; O[ct][3] *= alpha[3];
      }
      const bf16x8 pA = *(const bf16x8*)&smP[wave * 640 + l15 * 40 + quad * 8];
      #pragma unroll
      for (int ct = 0; ct < 8; ++ct) {
        const bf16x8 vf = *(const bf16x8*)&VtS[(ct * 16 + l15) * 40 + quad * 8];
        O[ct] = mfma16(pA, vf, O[ct]);
      }
    }
  }

  // write UNNORMALIZED partial O (bf16) + m,l (fp32); waves that computed
  // nothing naturally write O=0, m=-1e30, l=0 (combine weight = 0).
  #pragma unroll
  for (int r = 0; r < 4; ++r)
    #pragma unroll
    for (int ct = 0; ct < 8; ++ct)
      op[(quad * 4 + r) * 128 + ct * 16 + l15] = bf16_rne(O[ct][r]);
  if (l15 == 0) {
    #pragma unroll
    for (int r = 0; r < 4; ++r) {
      ml[(quad * 4 + r) * 2]     = mstate[r];
      ml[(quad * 4 + r) * 2 + 1] = lstate[r];
    }
  }
}

// ---------------------------------------------------------------------------
// Kernel 3: combine 4 split-K partials per q-row (unchanged from round 6).
// ---------------------------------------------------------------------------
__global__ __launch_bounds__(256) void attn_combine(
    const ushort* __restrict__ Opart, const float* __restrict__ mlpart,
    float* __restrict__ out)
{
  const int idx = blockIdx.x * 256 + threadIdx.x;   // 0..524287
  const int c4  = idx & 31;
  const int r   = idx >> 5;
  const int t   = r & 2047;
  const int qt  = t >> 4, r16 = t & 15;
  const size_t pb = ((size_t)((r >> 11) * 128 + qt)) * SEG_;

  float m[SEG_], l[SEG_];
  #pragma unroll
  for (int s = 0; s < SEG_; ++s) {
    m[s] = mlpart[(pb + s) * 32 + r16 * 2];
    l[s] = mlpart[(pb + s) * 32 + r16 * 2 + 1];
  }
  float M = m[0];
  #pragma unroll
  for (int s = 1; s < SEG_; ++s) M = fmaxf(M, m[s]);
  float w[SEG_], L = 0.f;
  #pragma unroll
  for (int s = 0; s < SEG_; ++s) {
    w[s] = __expf(m[s] - M);
    L += l[s] * w[s];
  }
  float4 acc = make_float4(0.f, 0.f, 0.f, 0.f);
  #pragma unroll
  for (int s = 0; s < SEG_; ++s) {
    const ushort4 o = *(const ushort4*)(Opart + (pb + s) * 2048 + r16 * 128 + c4 * 4);
    acc.x += w[s] * bf16_tof(o.x);
    acc.y += w[s] * bf16_tof(o.y);
    acc.z += w[s] * bf16_tof(o.z);
    acc.w += w[s] * bf16_tof(o.w);
  }
  const float inv = 1.0f / L;
  *(float4*)(out + (size_t)r * H_ + c4 * 4) =
      make_float4(acc.x * inv, acc.y * inv, acc.z * inv, acc.w * inv);
}

// ---------------------------------------------------------------------------
extern "C" void kernel_launch(void* const* d_in, const int* in_sizes, int n_in,
                              void* d_out, int out_size, void* d_ws, size_t ws_size,
                              hipStream_t stream) {
  (void)in_sizes; (void)n_in; (void)out_size; (void)ws_size;
  const float* x  = (const float*)d_in[0];
  const float* Wq = (const float*)d_in[1];
  const float* Wk = (const float*)d_in[2];
  const float* Wv = (const float*)d_in[3];
  float* out = (float*)d_out;

  ushort* qhb = (ushort*)d_ws;
  ushort* qlb = qhb + (size_t)M_ * H_;
  ushort* khb = qlb + (size_t)M_ * H_;
  ushort* klb = khb + (size_t)M_ * H_;
  ushort* vTb = klb + (size_t)M_ * H_;
  ushort* whT = vTb + (size_t)M_ * H_;
  ushort* wlT = whT + (size_t)3 * H_ * E_;
  ushort* Opart = wlT + (size_t)3 * H_ * E_;
  float*  mlpart = (float*)(Opart + (size_t)B_ * 128 * SEG_ * 2048);

  wsplit<<<dim3(192), 256, 0, stream>>>(Wq, Wk, Wv, whT, wlT);
  proj_fused<<<dim3(M_/64, 2), 256, 0, stream>>>(x, whT, wlT,
                                                 qhb, qlb, khb, klb, vTb);
  attn_flash<<<dim3(B_*SEG_, 32), 256, 0, stream>>>(qhb, qlb, khb, klb, vTb,
                                                    Opart, mlpart);
  attn_combine<<<dim3(2048), 256, 0, stream>>>(Opart, mlpart, out);
}

// Round 8
// 184.906 us; speedup vs baseline: 4.0010x; 1.0072x over previous
//
#include <hip/hip_runtime.h>
#include <hip/hip_bf16.h>
#include <math.h>

#define B_ 8
#define T_ 2048
#define E_ 1024
#define H_ 128
#define M_ (B_*T_)              // 16384
#define SCALE_ 45.25483399593904f   // sqrt(2048) per reference
#define SEG_ 4                      // key-range split factor for attention

typedef __attribute__((ext_vector_type(8))) short bf16x8;
typedef __attribute__((ext_vector_type(4))) float f32x4;

#define mfma16(A, Bv, C) __builtin_amdgcn_mfma_f32_16x16x32_bf16((A), (Bv), (C), 0, 0, 0)

// ---- fragment-order flat indices (ushort elements) -------------------------
// Shared by producer AND consumer to avoid index-mismatch bugs (r2/r4 class).
// lane = quad*16 + l15 throughout.
// W-frag (proj B operand): g = mat*8+nt (0..23), kc = k/32 (0..31);
//   element (n = (g&7)*16 + l15, k = kc*32 + quad*8 + j)
#define FRAGW(g, kc, lane)  ((((size_t)(g)*32 + (kc))*64 + (lane))*8)
// K-frag (attn QK B operand): kt16 = key/16 (0..127), kc = h/32 (0..3);
//   element (key = kt16*16 + l15, h = kc*32 + quad*8 + j)
#define FRAGK(b, kt16, kc, lane) (((((size_t)(b)*128 + (kt16))*4 + (kc))*64 + (lane))*8)
// V-frag (attn PV B operand): ht = h/16 (0..7), kt32 = key/32 (0..63);
//   element (h = ht*16 + l15, key = kt32*32 + quad*8 + j)
#define FRAGV(b, ht, kt32, lane) (((((size_t)(b)*8 + (ht))*64 + (kt32))*64 + (lane))*8)

__device__ __forceinline__ ushort bf16_rne(float f) {
  unsigned u = __float_as_uint(f);
  u += 0x7fffu + ((u >> 16) & 1u);
  return (ushort)(u >> 16);
}
__device__ __forceinline__ float bf16_tof(ushort h) {
  return __uint_as_float(((unsigned)h) << 16);
}

// DPP row_ror:N within 16-lane rows; rotate-reduce leaves result in all lanes.
template <int N>
__device__ __forceinline__ float ror16(float x) {
  return __uint_as_float((unsigned)__builtin_amdgcn_update_dpp(
      0, (int)__float_as_uint(x), 0x120 + N, 0xF, 0xF, true));
}
__device__ __forceinline__ float rowmax16(float x) {
  x = fmaxf(x, ror16<8>(x));
  x = fmaxf(x, ror16<4>(x));
  x = fmaxf(x, ror16<2>(x));
  x = fmaxf(x, ror16<1>(x));
  return x;
}
__device__ __forceinline__ float rowsum16(float x) {
  x += ror16<8>(x);
  x += ror16<4>(x);
  x += ror16<2>(x);
  x += ror16<1>(x);
  return x;
}

// ---------------------------------------------------------------------------
// Kernel 0: split W -> whT/wlT bf16 in PROJ-B FRAGMENT ORDER.
// thread idx enumerates (mat, nt, kc, lane) chunks; writes coalesced.
// ---------------------------------------------------------------------------
__global__ __launch_bounds__(256) void wsplit(
    const float* __restrict__ Wq, const float* __restrict__ Wk,
    const float* __restrict__ Wv,
    ushort* __restrict__ whT, ushort* __restrict__ wlT)
{
  const int idx  = blockIdx.x * 256 + threadIdx.x;  // 0..49151
  const int mat  = idx >> 14;                       // 16384 chunks per mat
  const int rem  = idx & 16383;
  const int nt   = rem >> 11;                       // 0..7
  const int kc   = (rem >> 6) & 31;                 // 0..31
  const int lane = rem & 63;
  const int quad = lane >> 4, l15 = lane & 15;
  const float* W = (mat == 0) ? Wq : (mat == 1) ? Wk : Wv;
  const int n  = nt * 16 + l15;
  const int k0 = kc * 32 + quad * 8;
  bf16x8 hv, lv;
  #pragma unroll
  for (int j = 0; j < 8; ++j) {
    const float f = W[(size_t)(k0 + j) * H_ + n];
    const ushort h = bf16_rne(f);
    hv[j] = (short)h;
    lv[j] = (short)bf16_rne(f - bf16_tof(h));
  }
  *(bf16x8*)(whT + (size_t)idx * 8) = hv;   // == FRAGW(mat*8+nt, kc, lane)
  *(bf16x8*)(wlT + (size_t)idx * 8) = lv;
}

// ---------------------------------------------------------------------------
// Kernel 1: fused QKV projection, round-8:
//  * B fragments loaded GLOBAL->REG from fragment-ordered whT/wlT, double-
//    buffered across k — no B LDS at all (r7: 7.57e6 LDS conflict cycles).
//  * A (x, split on the fly) in fragment-order LDS: frag reads 2-way (free),
//    writes 4-way on only 2 ops/thread/iter.
//  * epilogues emit q [t][h]; k in attn-K fragment order; v in attn-V
//    fragment order (via LDS transpose, stride 72 for alignment).
// Block: 64 m-rows x 192 n-cols (half). grid (256, 2).
// ---------------------------------------------------------------------------
#define PSTEP(KC, BH, BL, BHN, BLN) do {                                      \
    __syncthreads();                                                          \
    {                                                                         \
      const float f_[8] = {xf0.x, xf0.y, xf0.z, xf0.w,                        \
                           xf1.x, xf1.y, xf1.z, xf1.w};                       \
      bf16x8 hv_, lv_;                                                        \
      _Pragma("unroll")                                                       \
      for (int jj_ = 0; jj_ < 8; ++jj_) {                                     \
        const ushort h_ = bf16_rne(f_[jj_]);                                  \
        hv_[jj_] = (short)h_;                                                 \
        lv_[jj_] = (short)bf16_rne(f_[jj_] - bf16_tof(h_));                   \
      }                                                                       \
      *(bf16x8*)&AhS[ca * 8] = hv_;                                           \
      *(bf16x8*)&AlS[ca * 8] = lv_;                                           \
    }                                                                         \
    __syncthreads();                                                          \
    if ((KC) + 1 < 32) {                                                      \
      const float* s_ = x + (size_t)(m0 + arow) * E_ + ((KC) + 1) * 32 + akoff;\
      xf0 = *(const float4*)s_;                                               \
      xf1 = *(const float4*)(s_ + 4);                                         \
      _Pragma("unroll")                                                       \
      for (int j_ = 0; j_ < 3; ++j_) {                                        \
        const int g_ = g0 + 4 * j_;                                           \
        BHN[j_] = *(const bf16x8*)(whT + FRAGW(g_, (KC) + 1, lane));          \
        if (g_ < 16)                                                          \
          BLN[j_] = *(const bf16x8*)(wlT + FRAGW(g_, (KC) + 1, lane));        \
      }                                                                       \
    }                                                                         \
    bf16x8 a_h_[4], a_l_[4];                                                  \
    _Pragma("unroll")                                                         \
    for (int mt_ = 0; mt_ < 4; ++mt_) {                                       \
      a_h_[mt_] = *(const bf16x8*)&AhS[(((mt_ * 4 + quad) * 16) + l15) * 8];  \
      a_l_[mt_] = *(const bf16x8*)&AlS[(((mt_ * 4 + quad) * 16) + l15) * 8];  \
    }                                                                         \
    _Pragma("unroll")                                                         \
    for (int j_ = 0; j_ < 3; ++j_) {                                          \
      const int g_ = g0 + 4 * j_;                                             \
      if (g_ < 16) {                                                          \
        _Pragma("unroll")                                                     \
        for (int mt_ = 0; mt_ < 4; ++mt_) {                                   \
          acc[j_][mt_] = mfma16(a_h_[mt_], BH[j_], acc[j_][mt_]);             \
          acc[j_][mt_] = mfma16(a_h_[mt_], BL[j_], acc[j_][mt_]);             \
          acc[j_][mt_] = mfma16(a_l_[mt_], BH[j_], acc[j_][mt_]);             \
        }                                                                     \
      } else {                                                                \
        _Pragma("unroll")                                                     \
        for (int mt_ = 0; mt_ < 4; ++mt_)                                     \
          acc[j_][mt_] = mfma16(a_h_[mt_], BH[j_], acc[j_][mt_]);             \
      }                                                                       \
    }                                                                         \
  } while (0)

__global__ __launch_bounds__(256) void proj_fused(
    const float* __restrict__ x,
    const ushort* __restrict__ whT, const ushort* __restrict__ wlT,
    ushort* __restrict__ qh, ushort* __restrict__ ql,
    ushort* __restrict__ kfh, ushort* __restrict__ kfl,
    ushort* __restrict__ vF)
{
  const int m0   = blockIdx.x * 64;
  const int half = blockIdx.y;
  const int tid  = threadIdx.x;
  const int wave = tid >> 6, lane = tid & 63;
  const int quad = lane >> 4, l15 = lane & 15;

  __shared__ __align__(16) ushort SM[9216];    // A frags (4096) / smT (9216)
  ushort* AhS = SM;            // fragment order: chunk (mt*4+kq)*16+l15m
  ushort* AlS = SM + 2048;

  f32x4 acc[3][4];
  #pragma unroll
  for (int j = 0; j < 3; ++j)
    #pragma unroll
    for (int mt = 0; mt < 4; ++mt) acc[j][mt] = (f32x4){0.f, 0.f, 0.f, 0.f};

  const int arow  = tid >> 2;          // 0..63
  const int akoff = (tid & 3) * 8;     // 0,8,16,24
  const int ca    = ((arow >> 4) * 4 + (tid & 3)) * 16 + (arow & 15);
  const int g0    = half * 12 + wave;  // wave's n-tiles: g0, g0+4, g0+8

  float4 xf0, xf1;
  bf16x8 bhA[3], blA[3], bhB[3], blB[3];
  {
    const float* s = x + (size_t)(m0 + arow) * E_ + akoff;
    xf0 = *(const float4*)s;
    xf1 = *(const float4*)(s + 4);
    #pragma unroll
    for (int j = 0; j < 3; ++j) {
      const int g = g0 + 4 * j;
      bhA[j] = *(const bf16x8*)(whT + FRAGW(g, 0, lane));
      if (g < 16) blA[j] = *(const bf16x8*)(wlT + FRAGW(g, 0, lane));
    }
  }

  int kc = 0;
  while (true) {
    PSTEP(kc, bhA, blA, bhB, blB); if (++kc == 32) break;
    PSTEP(kc, bhB, blB, bhA, blA); if (++kc == 32) break;
  }

  // ---- epilogue: q -> [t][h]; k -> attn-K fragment order ----
  #pragma unroll
  for (int j = 0; j < 3; ++j) {
    const int g = g0 + 4 * j;
    if (g < 8) {                               // q
      const int ncol = g * 16 + l15;
      #pragma unroll
      for (int mt = 0; mt < 4; ++mt)
        #pragma unroll
        for (int r = 0; r < 4; ++r) {
          const float a = acc[j][mt][r];
          const ushort h = bf16_rne(a);
          const size_t off = (size_t)(m0 + mt * 16 + quad * 4 + r) * H_ + ncol;
          qh[off] = h;
          ql[off] = bf16_rne(a - bf16_tof(h));
        }
    } else if (g < 16) {                       // k -> fragment order
      const int hcol = (g - 8) * 16 + l15;
      const int kch  = hcol >> 5;
      const int qdh  = (hcol >> 3) & 3;
      const int jj   = hcol & 7;
      #pragma unroll
      for (int mt = 0; mt < 4; ++mt)
        #pragma unroll
        for (int r = 0; r < 4; ++r) {
          const float a = acc[j][mt][r];
          const int tg = m0 + mt * 16 + quad * 4 + r;
          const int bb = tg >> 11, tl = tg & 2047;
          const size_t ad = FRAGK(bb, tl >> 4, kch, qdh * 16 + (tl & 15)) + jj;
          const ushort h = bf16_rne(a);
          kfh[ad] = h;
          kfl[ad] = bf16_rne(a - bf16_tof(h));
        }
    }
  }
  // ---- epilogue: v (half 1) -> attn-V fragment order via LDS transpose ----
  if (half == 1) {
    __syncthreads();
    ushort* smT = SM;                          // [128][72] (72: 16B-aligned rows)
    #pragma unroll
    for (int j = 1; j < 3; ++j) {              // g = 16..23
      const int g = 12 + wave + 4 * j;
      const int hcol = (g - 16) * 16 + l15;
      #pragma unroll
      for (int mt = 0; mt < 4; ++mt)
        #pragma unroll
        for (int r = 0; r < 4; ++r)
          smT[hcol * 72 + mt * 16 + quad * 4 + r] = bf16_rne(acc[j][mt][r]);
    }
    __syncthreads();
    const int bb = m0 >> 11, t0 = m0 & 2047;
    #pragma unroll
    for (int u = 0; u < 4; ++u) {
      const int c   = u * 256 + tid;           // 1024 = 8 ht x 2 ktl x 64 lane
      const int ht  = c >> 7;
      const int ktl = (c >> 6) & 1;
      const int lv  = c & 63;
      const int qv  = lv >> 4, l15v = lv & 15;
      *(bf16x8*)(vF + FRAGV(bb, ht, (t0 >> 5) + ktl, lv)) =
          *(const bf16x8*)&smT[(ht * 16 + l15v) * 72 + ktl * 32 + qv * 8];
    }
  }
}

// ---------------------------------------------------------------------------
// Kernel 2: block flash attention, split-K (logic identical to passing r7;
// staging rewired to fragment-order inputs -> LINEAR LDS copies, conflict-
// free b128 reads/writes; LDS 29 KB -> 5 blocks/CU).
// ---------------------------------------------------------------------------
__global__ __launch_bounds__(256) void attn_flash(
    const ushort* __restrict__ qh, const ushort* __restrict__ ql,
    const ushort* __restrict__ kfh, const ushort* __restrict__ kfl,
    const ushort* __restrict__ vF,
    ushort* __restrict__ Opart, float* __restrict__ mlpart)
{
  const int b    = (int)blockIdx.x & 7;        // %8 -> XCD pin
  const int seg  = (int)blockIdx.x >> 3;
  const int qt   = 31 - (int)blockIdx.y;       // heavy first
  const int q0   = qt * 64;
  const int tid  = threadIdx.x;
  const int wave = tid >> 6, lane = tid & 63;
  const int quad = lane >> 4, l15 = lane & 15;
  const f32x4 z4 = (f32x4){0.f, 0.f, 0.f, 0.f};

  __shared__ __align__(16) ushort KhS[4096];   // [s(2)][kc(4)][lane][8] linear
  __shared__ __align__(16) ushort KlS[4096];
  __shared__ __align__(16) ushort VtS[4096];   // [ht(8)][lane][8] linear
  __shared__ __align__(16) ushort smP[4 * 640];

  const int ntiles = 2 * qt + 2;
  const int cnt    = (ntiles + SEG_ - 1) >> 2;
  const int jt0    = seg * cnt;
  const int jt1    = (jt0 + cnt < ntiles) ? (jt0 + cnt) : ntiles;

  const int q0w = q0 + wave * 16;
  const int ntw = ((q0w + 15) >> 5) + 1;
  const size_t pidx = ((size_t)(b * 128 + qt * 4 + wave)) * SEG_ + seg;
  ushort* op = Opart + pidx * 2048;
  float*  ml = mlpart + pidx * 32;

  if (jt0 >= jt1) {
    const bf16x8 zz = {0, 0, 0, 0, 0, 0, 0, 0};
    #pragma unroll
    for (int u = 0; u < 4; ++u)
      *(bf16x8*)(op + lane * 32 + u * 8) = zz;
    if (lane < 32) ml[lane] = (lane & 1) ? 0.f : -1e30f;
    return;
  }

  const size_t base = (size_t)b * T_ * H_;

  const ushort* qhp = qh + base + (size_t)(q0w + l15) * H_ + quad * 8;
  const ushort* qlp = ql + base + (size_t)(q0w + l15) * H_ + quad * 8;
  bf16x8 Qh[4], Ql[4];
  #pragma unroll
  for (int c = 0; c < 4; ++c) {
    Qh[c] = *(const bf16x8*)(qhp + c * 32);
    Ql[c] = *(const bf16x8*)(qlp + c * 32);
  }

  f32x4 O[8];
  #pragma unroll
  for (int i = 0; i < 8; ++i) O[i] = z4;
  float mstate[4] = {-1e30f, -1e30f, -1e30f, -1e30f};
  float lstate[4] = {0.f, 0.f, 0.f, 0.f};

  // staging regs; chunk c: K: (s = c>>8, kc = (c>>6)&3, lane_k = c&63)
  //               V: (ht = c>>6, lane_v = c&63)
  bf16x8 rkh[2], rkl[2], rv[2];
  {
    #pragma unroll
    for (int u = 0; u < 2; ++u) {
      const int c = u * 256 + tid;
      rkh[u] = *(const bf16x8*)(kfh + FRAGK(b, 2 * jt0 + (c >> 8), (c >> 6) & 3, c & 63));
      rkl[u] = *(const bf16x8*)(kfl + FRAGK(b, 2 * jt0 + (c >> 8), (c >> 6) & 3, c & 63));
      rv[u]  = *(const bf16x8*)(vF  + FRAGV(b, c >> 6, jt0, c & 63));
    }
  }

  for (int jt = jt0; jt < jt1; ++jt) {
    __syncthreads();
    #pragma unroll
    for (int u = 0; u < 2; ++u) {
      const int c = u * 256 + tid;
      *(bf16x8*)&KhS[c * 8] = rkh[u];
      *(bf16x8*)&KlS[c * 8] = rkl[u];
      *(bf16x8*)&VtS[c * 8] = rv[u];
    }
    __syncthreads();

    if (jt + 1 < jt1) {
      #pragma unroll
      for (int u = 0; u < 2; ++u) {
        const int c = u * 256 + tid;
        rkh[u] = *(const bf16x8*)(kfh + FRAGK(b, 2 * (jt + 1) + (c >> 8), (c >> 6) & 3, c & 63));
        rkl[u] = *(const bf16x8*)(kfl + FRAGK(b, 2 * (jt + 1) + (c >> 8), (c >> 6) & 3, c & 63));
        rv[u]  = *(const bf16x8*)(vF  + FRAGV(b, c >> 6, jt + 1, c & 63));
      }
    }

    if (jt < ntw) {
      const int k0 = jt * 32;
      f32x4 shh0 = z4, shh1 = z4, sx0 = z4, sx1 = z4;
      #pragma unroll
      for (int c = 0; c < 4; ++c) {
        const bf16x8 kh0 = *(const bf16x8*)&KhS[(c * 64 + lane) * 8];
        const bf16x8 kh1 = *(const bf16x8*)&KhS[((4 + c) * 64 + lane) * 8];
        const bf16x8 kl0 = *(const bf16x8*)&KlS[(c * 64 + lane) * 8];
        const bf16x8 kl1 = *(const bf16x8*)&KlS[((4 + c) * 64 + lane) * 8];
        shh0 = mfma16(Qh[c], kh0, shh0);
        shh1 = mfma16(Qh[c], kh1, shh1);
        sx0  = mfma16(Qh[c], kl0, sx0);
        sx1  = mfma16(Qh[c], kl1, sx1);
        sx0  = mfma16(Ql[c], kh0, sx0);
        sx1  = mfma16(Ql[c], kh1, sx1);
      }

      float s0[4], s1[4];
      #pragma unroll
      for (int r = 0; r < 4; ++r) {
        s0[r] = (shh0[r] + sx0[r]) * SCALE_;
        s1[r] = (shh1[r] + sx1[r]) * SCALE_;
      }
      if (jt == ntw - 1) {
        const int krel0 = k0 + l15      - q0w - quad * 4;
        const int krel1 = k0 + 16 + l15 - q0w - quad * 4;
        #pragma unroll
        for (int r = 0; r < 4; ++r) {
          if (krel0 > r) s0[r] = -1e30f;
          if (krel1 > r) s1[r] = -1e30f;
        }
      }

      float alpha[4];
      #pragma unroll
      for (int r = 0; r < 4; ++r) {
        const float rm   = rowmax16(fmaxf(s0[r], s1[r]));
        const float mnew = fmaxf(mstate[r], rm);
        alpha[r] = __expf(mstate[r] - mnew);
        mstate[r] = mnew;
        const float p0 = __expf(s0[r] - mnew);
        const float p1 = __expf(s1[r] - mnew);
        lstate[r] = lstate[r] * alpha[r] + rowsum16(p0 + p1);
        smP[wave * 640 + (quad * 4 + r) * 40 + l15]      = bf16_rne(p0);
        smP[wave * 640 + (quad * 4 + r) * 40 + 16 + l15] = bf16_rne(p1);
      }
      #pragma unroll
      for (int ct = 0; ct < 8; ++ct) {
        O[ct][0] *= alpha[0]; O[ct][1] *= alpha[1];
        O[ct][2] *= alpha[2]; O[ct][3] *= alpha[3];
      }
      const bf16x8 pA = *(const bf16x8*)&smP[wave * 640 + l15 * 40 + quad * 8];
      #pragma unroll
      for (int ct = 0; ct < 8; ++ct) {
        const bf16x8 vf = *(const bf16x8*)&VtS[(ct * 64 + lane) * 8];
        O[ct] = mfma16(pA, vf, O[ct]);
      }
    }
  }

  #pragma unroll
  for (int r = 0; r < 4; ++r)
    #pragma unroll
    for (int ct = 0; ct < 8; ++ct)
      op[(quad * 4 + r) * 128 + ct * 16 + l15] = bf16_rne(O[ct][r]);
  if (l15 == 0) {
    #pragma unroll
    for (int r = 0; r < 4; ++r) {
      ml[(quad * 4 + r) * 2]     = mstate[r];
      ml[(quad * 4 + r) * 2 + 1] = lstate[r];
    }
  }
}

// ---------------------------------------------------------------------------
// Kernel 3: combine 4 split-K partials per q-row (unchanged).
// ---------------------------------------------------------------------------
__global__ __launch_bounds__(256) void attn_combine(
    const ushort* __restrict__ Opart, const float* __restrict__ mlpart,
    float* __restrict__ out)
{
  const int idx = blockIdx.x * 256 + threadIdx.x;
  const int c4  = idx & 31;
  const int r   = idx >> 5;
  const int t   = r & 2047;
  const int qt  = t >> 4, r16 = t & 15;
  const size_t pb = ((size_t)((r >> 11) * 128 + qt)) * SEG_;

  float m[SEG_], l[SEG_];
  #pragma unroll
  for (int s = 0; s < SEG_; ++s) {
    m[s] = mlpart[(pb + s) * 32 + r16 * 2];
    l[s] = mlpart[(pb + s) * 32 + r16 * 2 + 1];
  }
  float M = m[0];
  #pragma unroll
  for (int s = 1; s < SEG_; ++s) M = fmaxf(M, m[s]);
  float w[SEG_], L = 0.f;
  #pragma unroll
  for (int s = 0; s < SEG_; ++s) {
    w[s] = __expf(m[s] - M);
    L += l[s] * w[s];
  }
  float4 acc = make_float4(0.f, 0.f, 0.f, 0.f);
  #pragma unroll
  for (int s = 0; s < SEG_; ++s) {
    const ushort4 o = *(const ushort4*)(Opart + (pb + s) * 2048 + r16 * 128 + c4 * 4);
    acc.x += w[s] * bf16_tof(o.x);
    acc.y += w[s] * bf16_tof(o.y);
    acc.z += w[s] * bf16_tof(o.z);
    acc.w += w[s] * bf16_tof(o.w);
  }
  const float inv = 1.0f / L;
  *(float4*)(out + (size_t)r * H_ + c4 * 4) =
      make_float4(acc.x * inv, acc.y * inv, acc.z * inv, acc.w * inv);
}

// ---------------------------------------------------------------------------
extern "C" void kernel_launch(void* const* d_in, const int* in_sizes, int n_in,
                              void* d_out, int out_size, void* d_ws, size_t ws_size,
                              hipStream_t stream) {
  (void)in_sizes; (void)n_in; (void)out_size; (void)ws_size;
  const float* x  = (const float*)d_in[0];
  const float* Wq = (const float*)d_in[1];
  const float* Wk = (const float*)d_in[2];
  const float* Wv = (const float*)d_in[3];
  float* out = (float*)d_out;

  // ws layout identical sizes to r7 (~39.9 MB), contents re-ordered:
  //   qh, ql            : M_*H_ each, [t][h]
  //   kfh, kfl          : M_*H_ each, attn-K fragment order
  //   vF                : M_*H_, attn-V fragment order
  //   whT, wlT          : 3*H_*E_ each, proj-B fragment order
  //   Opart, mlpart     : split-K partials
  ushort* qhb = (ushort*)d_ws;
  ushort* qlb = qhb + (size_t)M_ * H_;
  ushort* kfh = qlb + (size_t)M_ * H_;
  ushort* kfl = kfh + (size_t)M_ * H_;
  ushort* vFb = kfl + (size_t)M_ * H_;
  ushort* whT = vFb + (size_t)M_ * H_;
  ushort* wlT = whT + (size_t)3 * H_ * E_;
  ushort* Opart = wlT + (size_t)3 * H_ * E_;
  float*  mlpart = (float*)(Opart + (size_t)B_ * 128 * SEG_ * 2048);

  wsplit<<<dim3(192), 256, 0, stream>>>(Wq, Wk, Wv, whT, wlT);
  proj_fused<<<dim3(M_/64, 2), 256, 0, stream>>>(x, whT, wlT,
                                                 qhb, qlb, kfh, kfl, vFb);
  attn_flash<<<dim3(B_*SEG_, 32), 256, 0, stream>>>(qhb, qlb, kfh, kfl, vFb,
                                                    Opart, mlpart);
  attn_combine<<<dim3(2048), 256, 0, stream>>>(Opart, mlpart, out);
}